// Round 6
// baseline (398.578 us; speedup 1.0000x reference)
//
#include <hip/hip_runtime.h>
#include <stdint.h>

typedef unsigned short u16;
typedef __bf16 bfrag __attribute__((ext_vector_type(8)));   // 8 bf16 = 4 VGPRs (MFMA A/B, K=32)
typedef short sh4 __attribute__((ext_vector_type(4)));      // 4 bf16 = 2 VGPRs (MFMA A/B, K=16)
typedef short sh8 __attribute__((ext_vector_type(8)));
typedef float f32x4 __attribute__((ext_vector_type(4)));    // MFMA C/D

#define LOG2E 1.44269504088896340736f

__device__ __forceinline__ u16 f2bf(float f) {
    unsigned u = __builtin_bit_cast(unsigned, f);
    u = (u + 0x7fffu + ((u >> 16) & 1u)) >> 16;
    return (u16)u;
}
__device__ __forceinline__ float bf2f(u16 x) {
    unsigned u = ((unsigned)x) << 16;
    return __builtin_bit_cast(float, u);
}

__device__ __forceinline__ void gl_lds16(const u16* g, u16* l) {
#if __has_builtin(__builtin_amdgcn_global_load_lds)
    __builtin_amdgcn_global_load_lds(
        (const __attribute__((address_space(1))) unsigned int*)g,
        (__attribute__((address_space(3))) unsigned int*)l, 16, 0, 0);
#else
    *(uint4*)l = *(const uint4*)g;
#endif
}

template <int N>
__device__ __forceinline__ void waitcnt_vm() {
    if constexpr (N == 0)      asm volatile("s_waitcnt vmcnt(0)" ::: "memory");
    else if constexpr (N == 6) asm volatile("s_waitcnt vmcnt(6)" ::: "memory");
    else if constexpr (N == 8) asm volatile("s_waitcnt vmcnt(8)" ::: "memory");
}

// PV micro-op: O^T[16d][16q] += V^T-frag (A) * P^T-frag (B), K=16
__device__ __forceinline__ f32x4 pv_mfma(sh4 v, sh4 p, f32x4 c) {
#if __has_builtin(__builtin_amdgcn_mfma_f32_16x16x16bf16_1k)
    return __builtin_amdgcn_mfma_f32_16x16x16bf16_1k(v, p, c, 0, 0, 0);
#else
    sh8 a = {v.x, v.y, v.z, v.w, 0, 0, 0, 0};
    sh8 b = {p.x, p.y, p.z, p.w, 0, 0, 0, 0};
    return __builtin_amdgcn_mfma_f32_16x16x32_bf16(
        __builtin_bit_cast(bfrag, a), __builtin_bit_cast(bfrag, b), c, 0, 0, 0);
#endif
}

// pack 4 f32 -> 4 bf16 via hardware v_cvt_pk_bf16_f32 (RNE), 2 instrs
__device__ __forceinline__ sh4 pack4(const f32x4& v) {
    uint2 u;
    asm("v_cvt_pk_bf16_f32 %0, %1, %2" : "=v"(u.x) : "v"(v[0]), "v"(v[1]));
    asm("v_cvt_pk_bf16_f32 %0, %1, %2" : "=v"(u.y) : "v"(v[2]), "v"(v[3]));
    return __builtin_bit_cast(sh4, u);
}

// ---------------- fp32 -> bf16 elementwise ----------------
__global__ __launch_bounds__(256) void cvt_f32_bf16(const float* __restrict__ s,
                                                    u16* __restrict__ d, int n4) {
    int i = blockIdx.x * 256 + threadIdx.x;
    if (i < n4) {
        float4 v = ((const float4*)s)[i];
        uint2 o;
        o.x = (unsigned)f2bf(v.x) | ((unsigned)f2bf(v.y) << 16);
        o.y = (unsigned)f2bf(v.z) | ((unsigned)f2bf(v.w) << 16);
        ((uint2*)d)[i] = o;
    }
}

// ---------------- transpose + convert ----------------
__global__ __launch_bounds__(256) void transpose_cvt(const float* __restrict__ src,
                                                     u16* __restrict__ dst,
                                                     int rows, int cols) {
    __shared__ float tile[32][33];
    int c0 = blockIdx.x * 32, r0 = blockIdx.y * 32;
    int tx = threadIdx.x, ty = threadIdx.y;
#pragma unroll
    for (int i = 0; i < 32; i += 8)
        tile[ty + i][tx] = src[(size_t)(r0 + ty + i) * cols + c0 + tx];
    __syncthreads();
#pragma unroll
    for (int i = 0; i < 32; i += 8)
        dst[(size_t)(c0 + ty + i) * rows + r0 + tx] = f2bf(tile[tx][ty + i]);
}

// ---------------- 3-buffer phase-split GEMM: C[M][N] = A[M][K]*B[N][K]^T ------------
// BM=256 x BN=128, BK=64, 512 thr (8 waves 4Mx2N, per-wave 64x64), 3 LDS buffers
// (144 KB, 1 block/CU). v5 deltas vs gemm_p4 (R4, inferred ~715 TF):
//  - 3 buffers: stage target (t+2)%3 was fully consumed at tile t-1's END barrier,
//    so staging decouples from read retirement: issue at phase TOP (DMA starts a
//    full phase earlier), no mid-tile lgkm drain needed.
//  - per-ks phase split, stage spread (m248v2 fine-interleave, 16 MFMA/phase):
//      phase ks0: stage A@t+2 (4 gl_lds) | ds_read ks0 (8 b128) | 16 MFMA | barrier
//      phase ks1: stage B@t+2 (2 gl_lds) | ds_read ks1 (8 b128) | 16 MFMA
//                 | vmcnt(6) | barrier
//  - vmcnt ledger: at tile end outstanding = t+1's 6 + t+2's 6 = 12 -> vmcnt(6)
//    retires exactly tile t+1 (resident for next iter); t+2's 6 stay in flight.
//    Tail: no stage issued -> vmcnt(0) before last tile. Barriers block-uniform.
// LDS swizzle unchanged from p4 (R2/R4 measured SQ_LDS_BANK_CONFLICT = 0):
// chunk' = chunk ^ (row&7); global_load_lds dest linear, inverse XOR on source.
template <typename OutT>
__global__ __launch_bounds__(512, 1) void gemm_p5(const u16* __restrict__ A,
                                                  const u16* __restrict__ B,
                                                  OutT* __restrict__ C,
                                                  int K, int ldc) {
    constexpr int BM = 256, BN = 128;
    __shared__ __align__(16) u16 As[3][BM * 64];
    __shared__ __align__(16) u16 Bs[3][BN * 64];
    const int tid = threadIdx.x;
    const int wid = tid >> 6, lane = tid & 63;
    const int quad = lane >> 4, l16 = lane & 15;
    const int wm = wid >> 1, wn = wid & 1;
    const int bm = blockIdx.x * BM, bn = blockIdx.y * BN;
    const int NT = K >> 6;

    // stage source pointers (linear LDS dest chunk c -> inverse-swizzled global src);
    // persistent, advanced +64 per tile; always point at tile t+2's K-offset.
    const u16* aSrc[4];
    const u16* bSrc[2];
#pragma unroll
    for (int j = 0; j < 4; ++j) {
        int c = j * 512 + tid, row = c >> 3, ch = c & 7;
        aSrc[j] = A + (size_t)(bm + row) * K + (ch ^ (row & 7)) * 8;
    }
#pragma unroll
    for (int j = 0; j < 2; ++j) {
        int c = j * 512 + tid, row = c >> 3, ch = c & 7;
        bSrc[j] = B + (size_t)(bn + row) * K + (ch ^ (row & 7)) * 8;
    }

    // ds_read bases (u16 units); row stride 64, frag stride 16 rows = 1024
    const int swz = l16 & 7;
    const int aBase = (wm * 64 + l16) * 64;
    const int bBase = (wn * 64 + l16) * 64;
    const int c0 = (quad ^ swz) * 8;          // ks=0 swizzled chunk offset
    const int c1 = ((4 | quad) ^ swz) * 8;    // ks=1

    f32x4 acc[4][4] = {};

    // prologue: stage tile0 -> buf0, tile1 -> buf1; wait tile0 (6 newest in flight)
#pragma unroll
    for (int j = 0; j < 4; ++j) gl_lds16(aSrc[j], &As[0][(j * 512 + tid) * 8]);
#pragma unroll
    for (int j = 0; j < 2; ++j) gl_lds16(bSrc[j], &Bs[0][(j * 512 + tid) * 8]);
#pragma unroll
    for (int j = 0; j < 4; ++j) gl_lds16(aSrc[j] + 64, &As[1][(j * 512 + tid) * 8]);
#pragma unroll
    for (int j = 0; j < 2; ++j) gl_lds16(bSrc[j] + 64, &Bs[1][(j * 512 + tid) * 8]);
#pragma unroll
    for (int j = 0; j < 4; ++j) aSrc[j] += 128;  // -> tile 2
#pragma unroll
    for (int j = 0; j < 2; ++j) bSrc[j] += 128;
    waitcnt_vm<6>();
    __builtin_amdgcn_s_barrier();
    asm volatile("" ::: "memory");

    int cur = 0, st = 2;
    for (int t = 0; t < NT; ++t) {
        const u16* ab = &As[cur][0];
        const u16* bb = &Bs[cur][0];
        const bool stg = (t + 2 < NT);

        // ---- phase ks0: stage A@t+2 | ds_read ks0 | 16 MFMA ----
        if (stg) {
#pragma unroll
            for (int j = 0; j < 4; ++j) gl_lds16(aSrc[j], &As[st][(j * 512 + tid) * 8]);
        }
        bfrag a0[4], b0[4];
#pragma unroll
        for (int mf = 0; mf < 4; ++mf) a0[mf] = *(const bfrag*)&ab[aBase + mf * 1024 + c0];
#pragma unroll
        for (int nf = 0; nf < 4; ++nf) b0[nf] = *(const bfrag*)&bb[bBase + nf * 1024 + c0];
        __builtin_amdgcn_s_setprio(1);
#pragma unroll
        for (int mf = 0; mf < 4; ++mf)
#pragma unroll
            for (int nf = 0; nf < 4; ++nf)
                acc[mf][nf] = __builtin_amdgcn_mfma_f32_16x16x32_bf16(a0[mf], b0[nf], acc[mf][nf], 0, 0, 0);
        __builtin_amdgcn_s_setprio(0);
        __builtin_amdgcn_s_barrier();   // phase alignment (no buffer hazard w/ 3 bufs)
        asm volatile("" ::: "memory");

        // ---- phase ks1: stage B@t+2 | ds_read ks1 | 16 MFMA | vmcnt | barrier ----
        if (stg) {
#pragma unroll
            for (int j = 0; j < 2; ++j) gl_lds16(bSrc[j], &Bs[st][(j * 512 + tid) * 8]);
#pragma unroll
            for (int j = 0; j < 4; ++j) aSrc[j] += 64;
#pragma unroll
            for (int j = 0; j < 2; ++j) bSrc[j] += 64;
        }
        bfrag a1[4], b1[4];
#pragma unroll
        for (int mf = 0; mf < 4; ++mf) a1[mf] = *(const bfrag*)&ab[aBase + mf * 1024 + c1];
#pragma unroll
        for (int nf = 0; nf < 4; ++nf) b1[nf] = *(const bfrag*)&bb[bBase + nf * 1024 + c1];
        __builtin_amdgcn_s_setprio(1);
#pragma unroll
        for (int mf = 0; mf < 4; ++mf)
#pragma unroll
            for (int nf = 0; nf < 4; ++nf)
                acc[mf][nf] = __builtin_amdgcn_mfma_f32_16x16x32_bf16(a1[mf], b1[nf], acc[mf][nf], 0, 0, 0);
        __builtin_amdgcn_s_setprio(0);

        if (stg)                 waitcnt_vm<6>();  // retire t+1; t+2's 6 in flight
        else if (t + 1 < NT)     waitcnt_vm<0>();  // tail: drain for last tile
        if (t + 1 < NT) {
            __builtin_amdgcn_s_barrier();
            asm volatile("" ::: "memory");
        }
        cur = cur == 2 ? 0 : cur + 1;
        st  = st  == 2 ? 0 : st  + 1;
    }

#pragma unroll
    for (int mf = 0; mf < 4; ++mf)
#pragma unroll
        for (int nf = 0; nf < 4; ++nf)
#pragma unroll
            for (int r = 0; r < 4; ++r) {
                int row = bm + wm * 64 + mf * 16 + quad * 4 + r;
                int col = bn + wn * 64 + nf * 16 + l16;
                float v = acc[mf][nf][r];
                if constexpr (sizeof(OutT) == 2)
                    C[(size_t)row * ldc + col] = f2bf(v);
                else
                    C[(size_t)row * ldc + col] = v;
            }
}

// ---------------- RMSNorm + RoPE (q prescaled by softmax scale * log2e) ----------------
__global__ __launch_bounds__(256) void rmsrope(u16* __restrict__ qkv,
                                               const float* __restrict__ cosb,
                                               const float* __restrict__ sinb,
                                               const float* __restrict__ qw,
                                               const float* __restrict__ kw) {
    const float c1 = 0.08838834764831845f * LOG2E;
    int wave = threadIdx.x >> 6, lane = threadIdx.x & 63;
    int pi = blockIdx.x * 4 + wave;
    int m = pi / 20, hsel = pi % 20;
    int col0 = hsel < 16 ? hsel * 128 : 2048 + (hsel - 16) * 128;
    const float* w = hsel < 16 ? qw : kw;
    float sc = hsel < 16 ? c1 : 1.0f;
    int s = m & 2047;
    u16* p = qkv + (size_t)m * 3072 + col0;
    float x1 = bf2f(p[lane]), x2 = bf2f(p[lane + 64]);
    float ss = x1 * x1 + x2 * x2;
#pragma unroll
    for (int off = 32; off; off >>= 1) ss += __shfl_xor(ss, off, 64);
    float inv = rsqrtf(ss * (1.0f / 128.0f) + 1e-6f);
    float y1 = x1 * inv * w[lane], y2 = x2 * inv * w[lane + 64];
    const float* cp = cosb + (size_t)s * 128;
    const float* sp = sinb + (size_t)s * 128;
    float o1 = y1 * cp[lane] - y2 * sp[lane];
    float o2 = y2 * cp[lane + 64] + y1 * sp[lane + 64];
    p[lane] = f2bf(o1 * sc);
    p[lane + 64] = f2bf(o2 * sc);
}

// ---------------- V transpose ----------------
__global__ __launch_bounds__(256) void transpose_v(const u16* __restrict__ qkv,
                                                   u16* __restrict__ vT) {
    __shared__ u16 t[32][33];
    int bh = blockIdx.z, b = bh >> 2, kvh = bh & 3;
    int s0 = blockIdx.y * 32, d0 = blockIdx.x * 32;
    int tx = threadIdx.x, ty = threadIdx.y;
    const u16* src = qkv + (size_t)(b * 2048) * 3072 + 2560 + kvh * 128;
#pragma unroll
    for (int i = 0; i < 32; i += 8)
        t[ty + i][tx] = src[(size_t)(s0 + ty + i) * 3072 + d0 + tx];
    __syncthreads();
    u16* dst = vT + (size_t)bh * 128 * 2048;
#pragma unroll
    for (int i = 0; i < 32; i += 8)
        dst[(size_t)(d0 + ty + i) * 2048 + s0 + tx] = t[tx][ty + i];
}

// ---------------- causal flash attention v3 (unchanged this round) -------------------
__global__ __launch_bounds__(256, 2) void attn_kernel(const u16* __restrict__ qkv,
                                                      const u16* __restrict__ vT,
                                                      u16* __restrict__ out) {
    __shared__ u16 Ks[2][64 * 128];    // [buf][kv][16B-chunk ^ (kv&15)]
    __shared__ u16 VsT[2][128 * 64];   // [buf][d][16B-chunk ^ (d&7)]
    const int tid = threadIdx.x, wave = tid >> 6, lane = tid & 63;
    const int quad = lane >> 4, l16 = lane & 15;
    const int bh = blockIdx.x, b = bh >> 4, h = bh & 15, kvh = h >> 2;
    const int pair = blockIdx.y;
    const int qtA = pair, qtB = 31 - pair;
    const int NT = qtB + 1;            // KV tiles to sweep
    const size_t rowBase = (size_t)b * 2048;
    const int kcol0 = 2048 + kvh * 128;
    const u16* vTbase = vT + (size_t)(b * 4 + kvh) * 128 * 2048;

    const int qrowA = qtA * 64 + wave * 16 + l16;
    const int qrowB = qtB * 64 + wave * 16 + l16;

    // Q B-frags for both tiles (K=32): lane l16 holds d = ks*32 + quad*8 + j
    bfrag qa[4], qb[4];
    {
        const u16* qpA = qkv + (rowBase + qrowA) * 3072 + h * 128 + quad * 8;
        const u16* qpB = qkv + (rowBase + qrowB) * 3072 + h * 128 + quad * 8;
#pragma unroll
        for (int ks = 0; ks < 4; ++ks) qa[ks] = *(const bfrag*)(qpA + ks * 32);
#pragma unroll
        for (int ks = 0; ks < 4; ++ks) qb[ks] = *(const bfrag*)(qpB + ks * 32);
    }
    // single drain; re-materialize so the loop never gets a conservative vmcnt
    asm volatile("s_waitcnt vmcnt(0)" ::: "memory");
#pragma unroll
    for (int ks = 0; ks < 4; ++ks) {
        uint4 t = __builtin_bit_cast(uint4, qa[ks]);
        asm volatile("" : "+v"(t.x), "+v"(t.y), "+v"(t.z), "+v"(t.w));
        qa[ks] = __builtin_bit_cast(bfrag, t);
        uint4 u = __builtin_bit_cast(uint4, qb[ks]);
        asm volatile("" : "+v"(u.x), "+v"(u.y), "+v"(u.z), "+v"(u.w));
        qb[ks] = __builtin_bit_cast(bfrag, u);
    }

    // persistent stage source pointers (pre-swizzled), advanced 64 kv per tile
    const u16* kp[4];
    const u16* vp[4];
#pragma unroll
    for (int i = 0; i < 4; ++i) {  // Ks: 64 rows x 16 chunks
        int c = i * 256 + tid, kv = c >> 4, cp2 = c & 15;
        kp[i] = qkv + (rowBase + kv) * 3072 + kcol0 + (cp2 ^ (kv & 15)) * 8;
    }
#pragma unroll
    for (int i = 0; i < 4; ++i) {  // VsT: 128 rows x 8 chunks
        int c = i * 256 + tid, d = c >> 3, cp2 = c & 7;
        vp[i] = vTbase + (size_t)d * 2048 + (cp2 ^ (d & 7)) * 8;
    }

    f32x4 oA[8] = {}, oB[8] = {};
    float lA = 0.f, lB = 0.f;

    // stage tile 0 -> buf 0; advance ptrs to tile 1
#pragma unroll
    for (int i = 0; i < 4; ++i) gl_lds16(kp[i], &Ks[0][(i * 256 + tid) * 8]);
#pragma unroll
    for (int i = 0; i < 4; ++i) gl_lds16(vp[i], &VsT[0][(i * 256 + tid) * 8]);
#pragma unroll
    for (int i = 0; i < 4; ++i) { kp[i] += 64 * 3072; vp[i] += 64; }

#pragma unroll 1
    for (int kt = 0; kt < NT; ++kt) {
        const int cur = kt & 1;
        if (kt + 1 < NT) {
#pragma unroll
            for (int i = 0; i < 4; ++i) gl_lds16(kp[i], &Ks[cur ^ 1][(i * 256 + tid) * 8]);
#pragma unroll
            for (int i = 0; i < 4; ++i) gl_lds16(vp[i], &VsT[cur ^ 1][(i * 256 + tid) * 8]);
#pragma unroll
            for (int i = 0; i < 4; ++i) { kp[i] += 64 * 3072; vp[i] += 64; }
            waitcnt_vm<8>();
        } else {
            waitcnt_vm<0>();
        }
        __builtin_amdgcn_s_barrier();
        asm volatile("" ::: "memory");

        const int kv0 = kt * 64;
        const bool doA = (kt <= qtA);  // block-uniform

        // S^T = K * Q^T — one kf load feeds both q-tiles in the overlap region
        f32x4 saA[4] = {}, saB[4] = {};
        __builtin_amdgcn_s_setprio(1);
        if (doA) {
#pragma unroll
            for (int ks = 0; ks < 4; ++ks)
#pragma unroll
                for (int m = 0; m < 4; ++m) {
                    bfrag kf = *(const bfrag*)&Ks[cur][((m * 16 + l16) * 16 + ((ks * 4 + quad) ^ l16)) * 8];
                    saB[m] = __builtin_amdgcn_mfma_f32_16x16x32_bf16(kf, qb[ks], saB[m], 0, 0, 0);
                    saA[m] = __builtin_amdgcn_mfma_f32_16x16x32_bf16(kf, qa[ks], saA[m], 0, 0, 0);
                }
        } else {
#pragma unroll
            for (int ks = 0; ks < 4; ++ks)
#pragma unroll
                for (int m = 0; m < 4; ++m) {
                    bfrag kf = *(const bfrag*)&Ks[cur][((m * 16 + l16) * 16 + ((ks * 4 + quad) ^ l16)) * 8];
                    saB[m] = __builtin_amdgcn_mfma_f32_16x16x32_bf16(kf, qb[ks], saB[m], 0, 0, 0);
                }
        }
        __builtin_amdgcn_s_setprio(0);

        // no-max softmax (p = exp2(s), masked -> -3e38 underflows to 0), pack to bf16
        sh4 pfA[4], pfB[4];
        {
            if (kv0 + 63 > qtB * 64 + wave * 16) {  // B diagonal tile
#pragma unroll
                for (int m = 0; m < 4; ++m)
#pragma unroll
                    for (int r = 0; r < 4; ++r)
                        if (kv0 + m * 16 + quad * 4 + r > qrowB) saB[m][r] = -3e38f;
            }
            float rs = 0.f;
#pragma unroll
            for (int m = 0; m < 4; ++m)
#pragma unroll
                for (int r = 0; r < 4; ++r) {
                    float pe = exp2f(saB[m][r]);
                    saB[m][r] = pe;
                    rs += pe;
                }
            rs += __shfl_xor(rs, 16, 64);
            rs += __shfl_xor(rs, 32, 64);
            lB += rs;
#pragma unroll
            for (int m = 0; m < 4; ++m) pfB[m] = pack4(saB[m]);
        }
        if (doA) {
            if (kv0 + 63 > qtA * 64 + wave * 16) {  // A diagonal tile
#pragma unroll
                for (int m = 0; m < 4; ++m)
#pragma unroll
                    for (int r = 0; r < 4; ++r)
                        if (kv0 + m * 16 + quad * 4 + r > qrowA) saA[m][r] = -3e38f;
            }
            float rs = 0.f;
#pragma unroll
            for (int m = 0; m < 4; ++m)
#pragma unroll
                for (int r = 0; r < 4; ++r) {
                    float pe = exp2f(saA[m][r]);
                    saA[m][r] = pe;
                    rs += pe;
                }
            rs += __shfl_xor(rs, 16, 64);
            rs += __shfl_xor(rs, 32, 64);
            lA += rs;
#pragma unroll
            for (int m = 0; m < 4; ++m) pfA[m] = pack4(saA[m]);
        }

        // O^T += V^T * P^T — one vf load feeds both q-tiles in the overlap region
        __builtin_amdgcn_s_setprio(1);
        if (doA) {
#pragma unroll
            for (int k2 = 0; k2 < 4; ++k2)
#pragma unroll
                for (int dt = 0; dt < 8; ++dt) {
                    int d = dt * 16 + l16;
                    int ch = k2 * 2 + (quad >> 1);
                    sh4 vf = *(const sh4*)&VsT[cur][(d * 8 + (ch ^ (l16 & 7))) * 8 + (quad & 1) * 4];
                    oB[dt] = pv_mfma(vf, pfB[k2], oB[dt]);
                    oA[dt] = pv_mfma(vf, pfA[k2], oA[dt]);
                }
        } else {
#pragma unroll
            for (int k2 = 0; k2 < 4; ++k2)
#pragma unroll
                for (int dt = 0; dt < 8; ++dt) {
                    int d = dt * 16 + l16;
                    int ch = k2 * 2 + (quad >> 1);
                    sh4 vf = *(const sh4*)&VsT[cur][(d * 8 + (ch ^ (l16 & 7))) * 8 + (quad & 1) * 4];
                    oB[dt] = pv_mfma(vf, pfB[k2], oB[dt]);
                }
        }
        __builtin_amdgcn_s_setprio(0);
        asm volatile("" ::: "memory");
        __builtin_amdgcn_s_barrier();  // all reads of buf[cur] done before overwrite
    }

    // epilogue: normalize, pack, store 8B per (lane, dtile) for both q-tiles
    {
        float inv = 1.0f / lA;
        size_t orow = (rowBase + qrowA) * 2048 + h * 128 + quad * 4;
#pragma unroll
        for (int dt = 0; dt < 8; ++dt) {
            float a0 = oA[dt][0] * inv, a1 = oA[dt][1] * inv;
            float a2 = oA[dt][2] * inv, a3 = oA[dt][3] * inv;
            uint2 pk;
            asm("v_cvt_pk_bf16_f32 %0, %1, %2" : "=v"(pk.x) : "v"(a0), "v"(a1));
            asm("v_cvt_pk_bf16_f32 %0, %1, %2" : "=v"(pk.y) : "v"(a2), "v"(a3));
            *(uint2*)(out + orow + dt * 16) = pk;
        }
    }
    {
        float inv = 1.0f / lB;
        size_t orow = (rowBase + qrowB) * 2048 + h * 128 + quad * 4;
#pragma unroll
        for (int dt = 0; dt < 8; ++dt) {
            float a0 = oB[dt][0] * inv, a1 = oB[dt][1] * inv;
            float a2 = oB[dt][2] * inv, a3 = oB[dt][3] * inv;
            uint2 pk;
            asm("v_cvt_pk_bf16_f32 %0, %1, %2" : "=v"(pk.x) : "v"(a0), "v"(a1));
            asm("v_cvt_pk_bf16_f32 %0, %1, %2" : "=v"(pk.y) : "v"(a2), "v"(a3));
            *(uint2*)(out + orow + dt * 16) = pk;
        }
    }
}

extern "C" void kernel_launch(void* const* d_in, const int* in_sizes, int n_in,
                              void* d_out, int out_size, void* d_ws, size_t ws_size,
                              hipStream_t stream) {
    const float* hs   = (const float*)d_in[0];
    const float* cosb = (const float*)d_in[1];
    const float* sinb = (const float*)d_in[2];
    const float* Wq = (const float*)d_in[4];
    const float* Wk = (const float*)d_in[5];
    const float* Wv = (const float*)d_in[6];
    const float* Wo = (const float*)d_in[7];
    const float* qw = (const float*)d_in[8];
    const float* kw = (const float*)d_in[9];
    float* out = (float*)d_out;

    char* ws = (char*)d_ws;
    u16* hsb   = (u16*)(ws + 0);          // 16 MB: hs bf16; later reused as attn-out bf16
    u16* wqkvT = (u16*)(ws + 16777216);   // 12 MB
    u16* woT   = (u16*)(ws + 29360128);   // 8 MB
    u16* qkv   = (u16*)(ws + 37748736);   // 24 MB
    u16* vT    = (u16*)(ws + 62914560);   // 4 MB

    dim3 tb(32, 8);
    cvt_f32_bf16<<<8192, 256, 0, stream>>>(hs, hsb, 2097152);
    transpose_cvt<<<dim3(64, 64), tb, 0, stream>>>(Wq, wqkvT, 2048, 2048);
    transpose_cvt<<<dim3(16, 64), tb, 0, stream>>>(Wk, wqkvT + (size_t)2048 * 2048, 2048, 512);
    transpose_cvt<<<dim3(16, 64), tb, 0, stream>>>(Wv, wqkvT + (size_t)2560 * 2048, 2048, 512);
    transpose_cvt<<<dim3(64, 64), tb, 0, stream>>>(Wo, woT, 2048, 2048);

    // QKV projection: M=4096, N=3072, K=2048 -> 16x24 = 384 blocks of 512
    gemm_p5<u16><<<dim3(16, 24), 512, 0, stream>>>(hsb, wqkvT, qkv, 2048, 3072);

    rmsrope<<<20480, 256, 0, stream>>>(qkv, cosb, sinb, qw, kw);
    transpose_v<<<dim3(4, 64, 8), tb, 0, stream>>>(qkv, vT);

    attn_kernel<<<dim3(32, 16), 256, 0, stream>>>(qkv, vT, hsb);

    // O projection: M=4096, N=2048, K=2048 -> 16x16 = 256 blocks (all CUs busy)
    gemm_p5<float><<<dim3(16, 16), 512, 0, stream>>>(hsb, woT, out, 2048, 2048);
}

// Round 7
// 325.674 us; speedup vs baseline: 1.2239x; 1.2239x over previous
//
#include <hip/hip_runtime.h>
#include <stdint.h>

typedef unsigned short u16;
typedef __bf16 bfrag __attribute__((ext_vector_type(8)));   // 8 bf16 = 4 VGPRs (MFMA A/B, K=32)
typedef short sh4 __attribute__((ext_vector_type(4)));      // 4 bf16 = 2 VGPRs (MFMA A/B, K=16)
typedef short sh8 __attribute__((ext_vector_type(8)));
typedef float f32x4 __attribute__((ext_vector_type(4)));    // MFMA C/D

#define LOG2E 1.44269504088896340736f

__device__ __forceinline__ u16 f2bf(float f) {
    unsigned u = __builtin_bit_cast(unsigned, f);
    u = (u + 0x7fffu + ((u >> 16) & 1u)) >> 16;
    return (u16)u;
}
__device__ __forceinline__ float bf2f(u16 x) {
    unsigned u = ((unsigned)x) << 16;
    return __builtin_bit_cast(float, u);
}

__device__ __forceinline__ void gl_lds16(const u16* g, u16* l) {
#if __has_builtin(__builtin_amdgcn_global_load_lds)
    __builtin_amdgcn_global_load_lds(
        (const __attribute__((address_space(1))) unsigned int*)g,
        (__attribute__((address_space(3))) unsigned int*)l, 16, 0, 0);
#else
    *(uint4*)l = *(const uint4*)g;
#endif
}

template <int N>
__device__ __forceinline__ void waitcnt_vm() {
    if constexpr (N == 0)      asm volatile("s_waitcnt vmcnt(0)" ::: "memory");
    else if constexpr (N == 6) asm volatile("s_waitcnt vmcnt(6)" ::: "memory");
    else if constexpr (N == 7) asm volatile("s_waitcnt vmcnt(7)" ::: "memory");
    else if constexpr (N == 8) asm volatile("s_waitcnt vmcnt(8)" ::: "memory");
}

// PV micro-op: O^T[16d][16q] += V^T-frag (A) * P^T-frag (B), K=16
__device__ __forceinline__ f32x4 pv_mfma(sh4 v, sh4 p, f32x4 c) {
#if __has_builtin(__builtin_amdgcn_mfma_f32_16x16x16bf16_1k)
    return __builtin_amdgcn_mfma_f32_16x16x16bf16_1k(v, p, c, 0, 0, 0);
#else
    sh8 a = {v.x, v.y, v.z, v.w, 0, 0, 0, 0};
    sh8 b = {p.x, p.y, p.z, p.w, 0, 0, 0, 0};
    return __builtin_amdgcn_mfma_f32_16x16x32_bf16(
        __builtin_bit_cast(bfrag, a), __builtin_bit_cast(bfrag, b), c, 0, 0, 0);
#endif
}

// pack 4 f32 -> 4 bf16 via hardware v_cvt_pk_bf16_f32 (RNE), 2 instrs
__device__ __forceinline__ sh4 pack4(const f32x4& v) {
    uint2 u;
    asm("v_cvt_pk_bf16_f32 %0, %1, %2" : "=v"(u.x) : "v"(v[0]), "v"(v[1]));
    asm("v_cvt_pk_bf16_f32 %0, %1, %2" : "=v"(u.y) : "v"(v[2]), "v"(v[3]));
    return __builtin_bit_cast(sh4, u);
}

// ---------------- fp32 -> bf16 elementwise ----------------
__global__ __launch_bounds__(256) void cvt_f32_bf16(const float* __restrict__ s,
                                                    u16* __restrict__ d, int n4) {
    int i = blockIdx.x * 256 + threadIdx.x;
    if (i < n4) {
        float4 v = ((const float4*)s)[i];
        uint2 o;
        o.x = (unsigned)f2bf(v.x) | ((unsigned)f2bf(v.y) << 16);
        o.y = (unsigned)f2bf(v.z) | ((unsigned)f2bf(v.w) << 16);
        ((uint2*)d)[i] = o;
    }
}

// ---------------- transpose + convert ----------------
__global__ __launch_bounds__(256) void transpose_cvt(const float* __restrict__ src,
                                                     u16* __restrict__ dst,
                                                     int rows, int cols) {
    __shared__ float tile[32][33];
    int c0 = blockIdx.x * 32, r0 = blockIdx.y * 32;
    int tx = threadIdx.x, ty = threadIdx.y;
#pragma unroll
    for (int i = 0; i < 32; i += 8)
        tile[ty + i][tx] = src[(size_t)(r0 + ty + i) * cols + c0 + tx];
    __syncthreads();
#pragma unroll
    for (int i = 0; i < 32; i += 8)
        dst[(size_t)(c0 + ty + i) * rows + r0 + tx] = f2bf(tile[tx][ty + i]);
}

// ---------------- phase-split GEMM (R4-proven p4 schedule, BN templated) -----------
// C[M][N] = A[M][K]*B[N][K]^T.  BM=256, BK=64, 512 thr (8 waves 4Mx2N).
// BN=192 for QKV (grid 16x16 = 256 blocks: removes the 384-block 1.5-round tail,
// round-2 half-idle machine); BN=128 for O-proj (already exactly 256 blocks).
// Schedule per K-tile t (buf = t&1) — identical to R4's gemm_p4 (best measured):
//   RD all frags (ks0+ks1) -> regs; MFMA ks0; lgkm(0)+barrier (buf consumed);
//   STAGE t+2 -> same buf (DMA); MFMA ks1; vmcnt(VW)+barrier (t+1 resident,
//   t+2's VW in flight). LDS swizzle chunk^=(row&7) (measured 0 bank conflicts);
//   global_load_lds dest linear, inverse XOR on global source.
template <int BN, typename OutT>
__global__ __launch_bounds__(512, 1) void gemm_p4(const u16* __restrict__ A,
                                                  const u16* __restrict__ B,
                                                  OutT* __restrict__ C,
                                                  int K, int ldc) {
    constexpr int BM = 256;
    constexpr int NF = BN / 32;       // B frags per wave per ks (wave N-tile = BN/2)
    constexpr int LB = BN / 64;       // B stage loads per thread per tile
    constexpr int VW = 4 + LB;        // vmem ops per staged tile
    __shared__ __align__(16) u16 As[2][BM * 64];
    __shared__ __align__(16) u16 Bs[2][BN * 64];
    const int tid = threadIdx.x;
    const int wid = tid >> 6, lane = tid & 63;
    const int quad = lane >> 4, l16 = lane & 15;
    const int wm = wid >> 1, wn = wid & 1;
    const int bm = blockIdx.x * BM, bn = blockIdx.y * BN;
    const int NT = K >> 6;

    const u16* aSrc[4];
    const u16* bSrc[LB];
#pragma unroll
    for (int j = 0; j < 4; ++j) {
        int c = j * 512 + tid, row = c >> 3, ch = c & 7;
        aSrc[j] = A + (size_t)(bm + row) * K + (ch ^ (row & 7)) * 8;
    }
#pragma unroll
    for (int j = 0; j < LB; ++j) {
        int c = j * 512 + tid, row = c >> 3, ch = c & 7;
        bSrc[j] = B + (size_t)(bn + row) * K + (ch ^ (row & 7)) * 8;
    }

    const int swz = l16 & 7;
    const int aBase = (wm * 64 + l16) * 64;
    const int bBase = (wn * (BN / 2) + l16) * 64;
    const int c0 = (quad ^ swz) * 8;
    const int c1 = ((4 | quad) ^ swz) * 8;

    f32x4 acc[4][NF] = {};

#pragma unroll
    for (int j = 0; j < 4; ++j) gl_lds16(aSrc[j], &As[0][(j * 512 + tid) * 8]);
#pragma unroll
    for (int j = 0; j < LB; ++j) gl_lds16(bSrc[j], &Bs[0][(j * 512 + tid) * 8]);
#pragma unroll
    for (int j = 0; j < 4; ++j) gl_lds16(aSrc[j] + 64, &As[1][(j * 512 + tid) * 8]);
#pragma unroll
    for (int j = 0; j < LB; ++j) gl_lds16(bSrc[j] + 64, &Bs[1][(j * 512 + tid) * 8]);
    waitcnt_vm<VW>();
    __builtin_amdgcn_s_barrier();
    asm volatile("" ::: "memory");

    int koff = 128;
    for (int t = 0; t < NT; ++t) {
        const u16* ab = &As[t & 1][0];
        const u16* bb = &Bs[t & 1][0];

        bfrag a0[4], b0[NF], a1[4], b1[NF];
#pragma unroll
        for (int mf = 0; mf < 4; ++mf) a0[mf] = *(const bfrag*)&ab[aBase + mf * 1024 + c0];
#pragma unroll
        for (int nf = 0; nf < NF; ++nf) b0[nf] = *(const bfrag*)&bb[bBase + nf * 1024 + c0];
#pragma unroll
        for (int mf = 0; mf < 4; ++mf) a1[mf] = *(const bfrag*)&ab[aBase + mf * 1024 + c1];
#pragma unroll
        for (int nf = 0; nf < NF; ++nf) b1[nf] = *(const bfrag*)&bb[bBase + nf * 1024 + c1];

        __builtin_amdgcn_s_setprio(1);
#pragma unroll
        for (int mf = 0; mf < 4; ++mf)
#pragma unroll
            for (int nf = 0; nf < NF; ++nf)
                acc[mf][nf] = __builtin_amdgcn_mfma_f32_16x16x32_bf16(a0[mf], b0[nf], acc[mf][nf], 0, 0, 0);
        __builtin_amdgcn_s_setprio(0);

        asm volatile("s_waitcnt lgkmcnt(0)" ::: "memory");
        __builtin_amdgcn_s_barrier();
        asm volatile("" ::: "memory");

        if (t + 2 < NT) {
#pragma unroll
            for (int j = 0; j < 4; ++j) gl_lds16(aSrc[j] + koff, &As[t & 1][(j * 512 + tid) * 8]);
#pragma unroll
            for (int j = 0; j < LB; ++j) gl_lds16(bSrc[j] + koff, &Bs[t & 1][(j * 512 + tid) * 8]);
            koff += 64;
        }

        __builtin_amdgcn_s_setprio(1);
#pragma unroll
        for (int mf = 0; mf < 4; ++mf)
#pragma unroll
            for (int nf = 0; nf < NF; ++nf)
                acc[mf][nf] = __builtin_amdgcn_mfma_f32_16x16x32_bf16(a1[mf], b1[nf], acc[mf][nf], 0, 0, 0);
        __builtin_amdgcn_s_setprio(0);

        if (t + 2 < NT)      waitcnt_vm<VW>();
        else if (t + 1 < NT) waitcnt_vm<0>();
        if (t + 1 < NT) {
            __builtin_amdgcn_s_barrier();
            asm volatile("" ::: "memory");
        }
    }

#pragma unroll
    for (int mf = 0; mf < 4; ++mf)
#pragma unroll
        for (int nf = 0; nf < NF; ++nf)
#pragma unroll
            for (int r = 0; r < 4; ++r) {
                int row = bm + wm * 64 + mf * 16 + quad * 4 + r;
                int col = bn + wn * (BN / 2) + nf * 16 + l16;
                float v = acc[mf][nf][r];
                if constexpr (sizeof(OutT) == 2)
                    C[(size_t)row * ldc + col] = f2bf(v);
                else
                    C[(size_t)row * ldc + col] = v;
            }
}

// ---------------- RMSNorm + RoPE (q prescaled by softmax scale * log2e) ----------------
__global__ __launch_bounds__(256) void rmsrope(u16* __restrict__ qkv,
                                               const float* __restrict__ cosb,
                                               const float* __restrict__ sinb,
                                               const float* __restrict__ qw,
                                               const float* __restrict__ kw) {
    const float c1 = 0.08838834764831845f * LOG2E;
    int wave = threadIdx.x >> 6, lane = threadIdx.x & 63;
    int pi = blockIdx.x * 4 + wave;
    int m = pi / 20, hsel = pi % 20;
    int col0 = hsel < 16 ? hsel * 128 : 2048 + (hsel - 16) * 128;
    const float* w = hsel < 16 ? qw : kw;
    float sc = hsel < 16 ? c1 : 1.0f;
    int s = m & 2047;
    u16* p = qkv + (size_t)m * 3072 + col0;
    float x1 = bf2f(p[lane]), x2 = bf2f(p[lane + 64]);
    float ss = x1 * x1 + x2 * x2;
#pragma unroll
    for (int off = 32; off; off >>= 1) ss += __shfl_xor(ss, off, 64);
    float inv = rsqrtf(ss * (1.0f / 128.0f) + 1e-6f);
    float y1 = x1 * inv * w[lane], y2 = x2 * inv * w[lane + 64];
    const float* cp = cosb + (size_t)s * 128;
    const float* sp = sinb + (size_t)s * 128;
    float o1 = y1 * cp[lane] - y2 * sp[lane];
    float o2 = y2 * cp[lane + 64] + y1 * sp[lane + 64];
    p[lane] = f2bf(o1 * sc);
    p[lane + 64] = f2bf(o2 * sc);
}

// ---------------- V transpose ----------------
__global__ __launch_bounds__(256) void transpose_v(const u16* __restrict__ qkv,
                                                   u16* __restrict__ vT) {
    __shared__ u16 t[32][33];
    int bh = blockIdx.z, b = bh >> 2, kvh = bh & 3;
    int s0 = blockIdx.y * 32, d0 = blockIdx.x * 32;
    int tx = threadIdx.x, ty = threadIdx.y;
    const u16* src = qkv + (size_t)(b * 2048) * 3072 + 2560 + kvh * 128;
#pragma unroll
    for (int i = 0; i < 32; i += 8)
        t[ty + i][tx] = src[(size_t)(s0 + ty + i) * 3072 + d0 + tx];
    __syncthreads();
    u16* dst = vT + (size_t)bh * 128 * 2048;
#pragma unroll
    for (int i = 0; i < 32; i += 8)
        dst[(size_t)(d0 + ty + i) * 2048 + s0 + tx] = t[tx][ty + i];
}

// ---------------- causal flash attention v3 (unchanged) ------------------------------
__global__ __launch_bounds__(256, 2) void attn_kernel(const u16* __restrict__ qkv,
                                                      const u16* __restrict__ vT,
                                                      u16* __restrict__ out) {
    __shared__ u16 Ks[2][64 * 128];    // [buf][kv][16B-chunk ^ (kv&15)]
    __shared__ u16 VsT[2][128 * 64];   // [buf][d][16B-chunk ^ (d&7)]
    const int tid = threadIdx.x, wave = tid >> 6, lane = tid & 63;
    const int quad = lane >> 4, l16 = lane & 15;
    const int bh = blockIdx.x, b = bh >> 4, h = bh & 15, kvh = h >> 2;
    const int pair = blockIdx.y;
    const int qtA = pair, qtB = 31 - pair;
    const int NT = qtB + 1;            // KV tiles to sweep
    const size_t rowBase = (size_t)b * 2048;
    const int kcol0 = 2048 + kvh * 128;
    const u16* vTbase = vT + (size_t)(b * 4 + kvh) * 128 * 2048;

    const int qrowA = qtA * 64 + wave * 16 + l16;
    const int qrowB = qtB * 64 + wave * 16 + l16;

    bfrag qa[4], qb[4];
    {
        const u16* qpA = qkv + (rowBase + qrowA) * 3072 + h * 128 + quad * 8;
        const u16* qpB = qkv + (rowBase + qrowB) * 3072 + h * 128 + quad * 8;
#pragma unroll
        for (int ks = 0; ks < 4; ++ks) qa[ks] = *(const bfrag*)(qpA + ks * 32);
#pragma unroll
        for (int ks = 0; ks < 4; ++ks) qb[ks] = *(const bfrag*)(qpB + ks * 32);
    }
    asm volatile("s_waitcnt vmcnt(0)" ::: "memory");
#pragma unroll
    for (int ks = 0; ks < 4; ++ks) {
        uint4 t = __builtin_bit_cast(uint4, qa[ks]);
        asm volatile("" : "+v"(t.x), "+v"(t.y), "+v"(t.z), "+v"(t.w));
        qa[ks] = __builtin_bit_cast(bfrag, t);
        uint4 u = __builtin_bit_cast(uint4, qb[ks]);
        asm volatile("" : "+v"(u.x), "+v"(u.y), "+v"(u.z), "+v"(u.w));
        qb[ks] = __builtin_bit_cast(bfrag, u);
    }

    const u16* kp[4];
    const u16* vp[4];
#pragma unroll
    for (int i = 0; i < 4; ++i) {
        int c = i * 256 + tid, kv = c >> 4, cp2 = c & 15;
        kp[i] = qkv + (rowBase + kv) * 3072 + kcol0 + (cp2 ^ (kv & 15)) * 8;
    }
#pragma unroll
    for (int i = 0; i < 4; ++i) {
        int c = i * 256 + tid, d = c >> 3, cp2 = c & 7;
        vp[i] = vTbase + (size_t)d * 2048 + (cp2 ^ (d & 7)) * 8;
    }

    f32x4 oA[8] = {}, oB[8] = {};
    float lA = 0.f, lB = 0.f;

#pragma unroll
    for (int i = 0; i < 4; ++i) gl_lds16(kp[i], &Ks[0][(i * 256 + tid) * 8]);
#pragma unroll
    for (int i = 0; i < 4; ++i) gl_lds16(vp[i], &VsT[0][(i * 256 + tid) * 8]);
#pragma unroll
    for (int i = 0; i < 4; ++i) { kp[i] += 64 * 3072; vp[i] += 64; }

#pragma unroll 1
    for (int kt = 0; kt < NT; ++kt) {
        const int cur = kt & 1;
        if (kt + 1 < NT) {
#pragma unroll
            for (int i = 0; i < 4; ++i) gl_lds16(kp[i], &Ks[cur ^ 1][(i * 256 + tid) * 8]);
#pragma unroll
            for (int i = 0; i < 4; ++i) gl_lds16(vp[i], &VsT[cur ^ 1][(i * 256 + tid) * 8]);
#pragma unroll
            for (int i = 0; i < 4; ++i) { kp[i] += 64 * 3072; vp[i] += 64; }
            waitcnt_vm<8>();
        } else {
            waitcnt_vm<0>();
        }
        __builtin_amdgcn_s_barrier();
        asm volatile("" ::: "memory");

        const int kv0 = kt * 64;
        const bool doA = (kt <= qtA);  // block-uniform

        f32x4 saA[4] = {}, saB[4] = {};
        __builtin_amdgcn_s_setprio(1);
        if (doA) {
#pragma unroll
            for (int ks = 0; ks < 4; ++ks)
#pragma unroll
                for (int m = 0; m < 4; ++m) {
                    bfrag kf = *(const bfrag*)&Ks[cur][((m * 16 + l16) * 16 + ((ks * 4 + quad) ^ l16)) * 8];
                    saB[m] = __builtin_amdgcn_mfma_f32_16x16x32_bf16(kf, qb[ks], saB[m], 0, 0, 0);
                    saA[m] = __builtin_amdgcn_mfma_f32_16x16x32_bf16(kf, qa[ks], saA[m], 0, 0, 0);
                }
        } else {
#pragma unroll
            for (int ks = 0; ks < 4; ++ks)
#pragma unroll
                for (int m = 0; m < 4; ++m) {
                    bfrag kf = *(const bfrag*)&Ks[cur][((m * 16 + l16) * 16 + ((ks * 4 + quad) ^ l16)) * 8];
                    saB[m] = __builtin_amdgcn_mfma_f32_16x16x32_bf16(kf, qb[ks], saB[m], 0, 0, 0);
                }
        }
        __builtin_amdgcn_s_setprio(0);

        sh4 pfA[4], pfB[4];
        {
            if (kv0 + 63 > qtB * 64 + wave * 16) {
#pragma unroll
                for (int m = 0; m < 4; ++m)
#pragma unroll
                    for (int r = 0; r < 4; ++r)
                        if (kv0 + m * 16 + quad * 4 + r > qrowB) saB[m][r] = -3e38f;
            }
            float rs = 0.f;
#pragma unroll
            for (int m = 0; m < 4; ++m)
#pragma unroll
                for (int r = 0; r < 4; ++r) {
                    float pe = exp2f(saB[m][r]);
                    saB[m][r] = pe;
                    rs += pe;
                }
            rs += __shfl_xor(rs, 16, 64);
            rs += __shfl_xor(rs, 32, 64);
            lB += rs;
#pragma unroll
            for (int m = 0; m < 4; ++m) pfB[m] = pack4(saB[m]);
        }
        if (doA) {
            if (kv0 + 63 > qtA * 64 + wave * 16) {
#pragma unroll
                for (int m = 0; m < 4; ++m)
#pragma unroll
                    for (int r = 0; r < 4; ++r)
                        if (kv0 + m * 16 + quad * 4 + r > qrowA) saA[m][r] = -3e38f;
            }
            float rs = 0.f;
#pragma unroll
            for (int m = 0; m < 4; ++m)
#pragma unroll
                for (int r = 0; r < 4; ++r) {
                    float pe = exp2f(saA[m][r]);
                    saA[m][r] = pe;
                    rs += pe;
                }
            rs += __shfl_xor(rs, 16, 64);
            rs += __shfl_xor(rs, 32, 64);
            lA += rs;
#pragma unroll
            for (int m = 0; m < 4; ++m) pfA[m] = pack4(saA[m]);
        }

        __builtin_amdgcn_s_setprio(1);
        if (doA) {
#pragma unroll
            for (int k2 = 0; k2 < 4; ++k2)
#pragma unroll
                for (int dt = 0; dt < 8; ++dt) {
                    int d = dt * 16 + l16;
                    int ch = k2 * 2 + (quad >> 1);
                    sh4 vf = *(const sh4*)&VsT[cur][(d * 8 + (ch ^ (l16 & 7))) * 8 + (quad & 1) * 4];
                    oB[dt] = pv_mfma(vf, pfB[k2], oB[dt]);
                    oA[dt] = pv_mfma(vf, pfA[k2], oA[dt]);
                }
        } else {
#pragma unroll
            for (int k2 = 0; k2 < 4; ++k2)
#pragma unroll
                for (int dt = 0; dt < 8; ++dt) {
                    int d = dt * 16 + l16;
                    int ch = k2 * 2 + (quad >> 1);
                    sh4 vf = *(const sh4*)&VsT[cur][(d * 8 + (ch ^ (l16 & 7))) * 8 + (quad & 1) * 4];
                    oB[dt] = pv_mfma(vf, pfB[k2], oB[dt]);
                }
        }
        __builtin_amdgcn_s_setprio(0);
        asm volatile("" ::: "memory");
        __builtin_amdgcn_s_barrier();
    }

    {
        float inv = 1.0f / lA;
        size_t orow = (rowBase + qrowA) * 2048 + h * 128 + quad * 4;
#pragma unroll
        for (int dt = 0; dt < 8; ++dt) {
            float a0 = oA[dt][0] * inv, a1 = oA[dt][1] * inv;
            float a2 = oA[dt][2] * inv, a3 = oA[dt][3] * inv;
            uint2 pk;
            asm("v_cvt_pk_bf16_f32 %0, %1, %2" : "=v"(pk.x) : "v"(a0), "v"(a1));
            asm("v_cvt_pk_bf16_f32 %0, %1, %2" : "=v"(pk.y) : "v"(a2), "v"(a3));
            *(uint2*)(out + orow + dt * 16) = pk;
        }
    }
    {
        float inv = 1.0f / lB;
        size_t orow = (rowBase + qrowB) * 2048 + h * 128 + quad * 4;
#pragma unroll
        for (int dt = 0; dt < 8; ++dt) {
            float a0 = oB[dt][0] * inv, a1 = oB[dt][1] * inv;
            float a2 = oB[dt][2] * inv, a3 = oB[dt][3] * inv;
            uint2 pk;
            asm("v_cvt_pk_bf16_f32 %0, %1, %2" : "=v"(pk.x) : "v"(a0), "v"(a1));
            asm("v_cvt_pk_bf16_f32 %0, %1, %2" : "=v"(pk.y) : "v"(a2), "v"(a3));
            *(uint2*)(out + orow + dt * 16) = pk;
        }
    }
}

extern "C" void kernel_launch(void* const* d_in, const int* in_sizes, int n_in,
                              void* d_out, int out_size, void* d_ws, size_t ws_size,
                              hipStream_t stream) {
    const float* hs   = (const float*)d_in[0];
    const float* cosb = (const float*)d_in[1];
    const float* sinb = (const float*)d_in[2];
    const float* Wq = (const float*)d_in[4];
    const float* Wk = (const float*)d_in[5];
    const float* Wv = (const float*)d_in[6];
    const float* Wo = (const float*)d_in[7];
    const float* qw = (const float*)d_in[8];
    const float* kw = (const float*)d_in[9];
    float* out = (float*)d_out;

    char* ws = (char*)d_ws;
    u16* hsb   = (u16*)(ws + 0);          // 16 MB: hs bf16; later reused as attn-out bf16
    u16* wqkvT = (u16*)(ws + 16777216);   // 12 MB
    u16* woT   = (u16*)(ws + 29360128);   // 8 MB
    u16* qkv   = (u16*)(ws + 37748736);   // 24 MB
    u16* vT    = (u16*)(ws + 62914560);   // 4 MB

    dim3 tb(32, 8);
    cvt_f32_bf16<<<8192, 256, 0, stream>>>(hs, hsb, 2097152);
    transpose_cvt<<<dim3(64, 64), tb, 0, stream>>>(Wq, wqkvT, 2048, 2048);
    transpose_cvt<<<dim3(16, 64), tb, 0, stream>>>(Wk, wqkvT + (size_t)2048 * 2048, 2048, 512);
    transpose_cvt<<<dim3(16, 64), tb, 0, stream>>>(Wv, wqkvT + (size_t)2560 * 2048, 2048, 512);
    transpose_cvt<<<dim3(64, 64), tb, 0, stream>>>(Wo, woT, 2048, 2048);

    // QKV projection: M=4096, N=3072, K=2048 -> BN=192: 16x16 = 256 blocks (no tail)
    gemm_p4<192, u16><<<dim3(16, 16), 512, 0, stream>>>(hsb, wqkvT, qkv, 2048, 3072);

    rmsrope<<<20480, 256, 0, stream>>>(qkv, cosb, sinb, qw, kw);
    transpose_v<<<dim3(4, 64, 8), tb, 0, stream>>>(qkv, vT);

    attn_kernel<<<dim3(32, 16), 256, 0, stream>>>(qkv, vT, hsb);

    // O projection: M=4096, N=2048, K=2048 -> BN=128: 16x16 = 256 blocks
    gemm_p4<128, float><<<dim3(16, 16), 512, 0, stream>>>(hsb, woT, out, 2048, 2048);
}

// Round 8
// 321.846 us; speedup vs baseline: 1.2384x; 1.0119x over previous
//
#include <hip/hip_runtime.h>
#include <stdint.h>

typedef unsigned short u16;
typedef __bf16 bfrag __attribute__((ext_vector_type(8)));   // 8 bf16 = 4 VGPRs (MFMA A/B, K=32)
typedef short sh4 __attribute__((ext_vector_type(4)));      // 4 bf16 = 2 VGPRs (MFMA A/B, K=16)
typedef short sh8 __attribute__((ext_vector_type(8)));
typedef float f32x4 __attribute__((ext_vector_type(4)));    // MFMA C/D

#define LOG2E 1.44269504088896340736f

__device__ __forceinline__ u16 f2bf(float f) {
    unsigned u = __builtin_bit_cast(unsigned, f);
    u = (u + 0x7fffu + ((u >> 16) & 1u)) >> 16;
    return (u16)u;
}
__device__ __forceinline__ float bf2f(u16 x) {
    unsigned u = ((unsigned)x) << 16;
    return __builtin_bit_cast(float, u);
}

__device__ __forceinline__ void gl_lds16(const u16* g, u16* l) {
#if __has_builtin(__builtin_amdgcn_global_load_lds)
    __builtin_amdgcn_global_load_lds(
        (const __attribute__((address_space(1))) unsigned int*)g,
        (__attribute__((address_space(3))) unsigned int*)l, 16, 0, 0);
#else
    *(uint4*)l = *(const uint4*)g;
#endif
}

template <int N>
__device__ __forceinline__ void waitcnt_vm() {
    if constexpr (N == 0)      asm volatile("s_waitcnt vmcnt(0)" ::: "memory");
    else if constexpr (N == 4) asm volatile("s_waitcnt vmcnt(4)" ::: "memory");
    else if constexpr (N == 5) asm volatile("s_waitcnt vmcnt(5)" ::: "memory");
    else if constexpr (N == 6) asm volatile("s_waitcnt vmcnt(6)" ::: "memory");
    else if constexpr (N == 7) asm volatile("s_waitcnt vmcnt(7)" ::: "memory");
    else if constexpr (N == 8) asm volatile("s_waitcnt vmcnt(8)" ::: "memory");
}

// PV micro-op: O^T[16d][16q] += V^T-frag (A) * P^T-frag (B), K=16
__device__ __forceinline__ f32x4 pv_mfma(sh4 v, sh4 p, f32x4 c) {
#if __has_builtin(__builtin_amdgcn_mfma_f32_16x16x16bf16_1k)
    return __builtin_amdgcn_mfma_f32_16x16x16bf16_1k(v, p, c, 0, 0, 0);
#else
    sh8 a = {v.x, v.y, v.z, v.w, 0, 0, 0, 0};
    sh8 b = {p.x, p.y, p.z, p.w, 0, 0, 0, 0};
    return __builtin_amdgcn_mfma_f32_16x16x32_bf16(
        __builtin_bit_cast(bfrag, a), __builtin_bit_cast(bfrag, b), c, 0, 0, 0);
#endif
}

// pack 4 f32 -> 4 bf16 via hardware v_cvt_pk_bf16_f32 (RNE), 2 instrs
__device__ __forceinline__ sh4 pack4(const f32x4& v) {
    uint2 u;
    asm("v_cvt_pk_bf16_f32 %0, %1, %2" : "=v"(u.x) : "v"(v[0]), "v"(v[1]));
    asm("v_cvt_pk_bf16_f32 %0, %1, %2" : "=v"(u.y) : "v"(v[2]), "v"(v[3]));
    return __builtin_bit_cast(sh4, u);
}

// ---------------- fp32 -> bf16 elementwise ----------------
__global__ __launch_bounds__(256) void cvt_f32_bf16(const float* __restrict__ s,
                                                    u16* __restrict__ d, int n4) {
    int i = blockIdx.x * 256 + threadIdx.x;
    if (i < n4) {
        float4 v = ((const float4*)s)[i];
        uint2 o;
        o.x = (unsigned)f2bf(v.x) | ((unsigned)f2bf(v.y) << 16);
        o.y = (unsigned)f2bf(v.z) | ((unsigned)f2bf(v.w) << 16);
        ((uint2*)d)[i] = o;
    }
}

// ---------------- transpose + convert ----------------
__global__ __launch_bounds__(256) void transpose_cvt(const float* __restrict__ src,
                                                     u16* __restrict__ dst,
                                                     int rows, int cols) {
    __shared__ float tile[32][33];
    int c0 = blockIdx.x * 32, r0 = blockIdx.y * 32;
    int tx = threadIdx.x, ty = threadIdx.y;
#pragma unroll
    for (int i = 0; i < 32; i += 8)
        tile[ty + i][tx] = src[(size_t)(r0 + ty + i) * cols + c0 + tx];
    __syncthreads();
#pragma unroll
    for (int i = 0; i < 32; i += 8)
        dst[(size_t)(c0 + ty + i) * rows + r0 + tx] = f2bf(tile[tx][ty + i]);
}

// ---------------- phase-split GEMM (R4-proven p4 schedule, BN templated) -----------
// Unchanged from R7 (best measured: total 325.7 us with this config).
template <int BN, typename OutT>
__global__ __launch_bounds__(512, 1) void gemm_p4(const u16* __restrict__ A,
                                                  const u16* __restrict__ B,
                                                  OutT* __restrict__ C,
                                                  int K, int ldc) {
    constexpr int BM = 256;
    constexpr int NF = BN / 32;
    constexpr int LB = BN / 64;
    constexpr int VW = 4 + LB;
    __shared__ __align__(16) u16 As[2][BM * 64];
    __shared__ __align__(16) u16 Bs[2][BN * 64];
    const int tid = threadIdx.x;
    const int wid = tid >> 6, lane = tid & 63;
    const int quad = lane >> 4, l16 = lane & 15;
    const int wm = wid >> 1, wn = wid & 1;
    const int bm = blockIdx.x * BM, bn = blockIdx.y * BN;
    const int NT = K >> 6;

    const u16* aSrc[4];
    const u16* bSrc[LB];
#pragma unroll
    for (int j = 0; j < 4; ++j) {
        int c = j * 512 + tid, row = c >> 3, ch = c & 7;
        aSrc[j] = A + (size_t)(bm + row) * K + (ch ^ (row & 7)) * 8;
    }
#pragma unroll
    for (int j = 0; j < LB; ++j) {
        int c = j * 512 + tid, row = c >> 3, ch = c & 7;
        bSrc[j] = B + (size_t)(bn + row) * K + (ch ^ (row & 7)) * 8;
    }

    const int swz = l16 & 7;
    const int aBase = (wm * 64 + l16) * 64;
    const int bBase = (wn * (BN / 2) + l16) * 64;
    const int c0 = (quad ^ swz) * 8;
    const int c1 = ((4 | quad) ^ swz) * 8;

    f32x4 acc[4][NF] = {};

#pragma unroll
    for (int j = 0; j < 4; ++j) gl_lds16(aSrc[j], &As[0][(j * 512 + tid) * 8]);
#pragma unroll
    for (int j = 0; j < LB; ++j) gl_lds16(bSrc[j], &Bs[0][(j * 512 + tid) * 8]);
#pragma unroll
    for (int j = 0; j < 4; ++j) gl_lds16(aSrc[j] + 64, &As[1][(j * 512 + tid) * 8]);
#pragma unroll
    for (int j = 0; j < LB; ++j) gl_lds16(bSrc[j] + 64, &Bs[1][(j * 512 + tid) * 8]);
    waitcnt_vm<VW>();
    __builtin_amdgcn_s_barrier();
    asm volatile("" ::: "memory");

    int koff = 128;
    for (int t = 0; t < NT; ++t) {
        const u16* ab = &As[t & 1][0];
        const u16* bb = &Bs[t & 1][0];

        bfrag a0[4], b0[NF], a1[4], b1[NF];
#pragma unroll
        for (int mf = 0; mf < 4; ++mf) a0[mf] = *(const bfrag*)&ab[aBase + mf * 1024 + c0];
#pragma unroll
        for (int nf = 0; nf < NF; ++nf) b0[nf] = *(const bfrag*)&bb[bBase + nf * 1024 + c0];
#pragma unroll
        for (int mf = 0; mf < 4; ++mf) a1[mf] = *(const bfrag*)&ab[aBase + mf * 1024 + c1];
#pragma unroll
        for (int nf = 0; nf < NF; ++nf) b1[nf] = *(const bfrag*)&bb[bBase + nf * 1024 + c1];

        __builtin_amdgcn_s_setprio(1);
#pragma unroll
        for (int mf = 0; mf < 4; ++mf)
#pragma unroll
            for (int nf = 0; nf < NF; ++nf)
                acc[mf][nf] = __builtin_amdgcn_mfma_f32_16x16x32_bf16(a0[mf], b0[nf], acc[mf][nf], 0, 0, 0);
        __builtin_amdgcn_s_setprio(0);

        asm volatile("s_waitcnt lgkmcnt(0)" ::: "memory");
        __builtin_amdgcn_s_barrier();
        asm volatile("" ::: "memory");

        if (t + 2 < NT) {
#pragma unroll
            for (int j = 0; j < 4; ++j) gl_lds16(aSrc[j] + koff, &As[t & 1][(j * 512 + tid) * 8]);
#pragma unroll
            for (int j = 0; j < LB; ++j) gl_lds16(bSrc[j] + koff, &Bs[t & 1][(j * 512 + tid) * 8]);
            koff += 64;
        }

        __builtin_amdgcn_s_setprio(1);
#pragma unroll
        for (int mf = 0; mf < 4; ++mf)
#pragma unroll
            for (int nf = 0; nf < NF; ++nf)
                acc[mf][nf] = __builtin_amdgcn_mfma_f32_16x16x32_bf16(a1[mf], b1[nf], acc[mf][nf], 0, 0, 0);
        __builtin_amdgcn_s_setprio(0);

        if (t + 2 < NT)      waitcnt_vm<VW>();
        else if (t + 1 < NT) waitcnt_vm<0>();
        if (t + 1 < NT) {
            __builtin_amdgcn_s_barrier();
            asm volatile("" ::: "memory");
        }
    }

#pragma unroll
    for (int mf = 0; mf < 4; ++mf)
#pragma unroll
        for (int nf = 0; nf < NF; ++nf)
#pragma unroll
            for (int r = 0; r < 4; ++r) {
                int row = bm + wm * 64 + mf * 16 + quad * 4 + r;
                int col = bn + wn * (BN / 2) + nf * 16 + l16;
                float v = acc[mf][nf][r];
                if constexpr (sizeof(OutT) == 2)
                    C[(size_t)row * ldc + col] = f2bf(v);
                else
                    C[(size_t)row * ldc + col] = v;
            }
}

// ---------------- RMSNorm + RoPE (q prescaled by softmax scale * log2e) ----------------
__global__ __launch_bounds__(256) void rmsrope(u16* __restrict__ qkv,
                                               const float* __restrict__ cosb,
                                               const float* __restrict__ sinb,
                                               const float* __restrict__ qw,
                                               const float* __restrict__ kw) {
    const float c1 = 0.08838834764831845f * LOG2E;
    int wave = threadIdx.x >> 6, lane = threadIdx.x & 63;
    int pi = blockIdx.x * 4 + wave;
    int m = pi / 20, hsel = pi % 20;
    int col0 = hsel < 16 ? hsel * 128 : 2048 + (hsel - 16) * 128;
    const float* w = hsel < 16 ? qw : kw;
    float sc = hsel < 16 ? c1 : 1.0f;
    int s = m & 2047;
    u16* p = qkv + (size_t)m * 3072 + col0;
    float x1 = bf2f(p[lane]), x2 = bf2f(p[lane + 64]);
    float ss = x1 * x1 + x2 * x2;
#pragma unroll
    for (int off = 32; off; off >>= 1) ss += __shfl_xor(ss, off, 64);
    float inv = rsqrtf(ss * (1.0f / 128.0f) + 1e-6f);
    float y1 = x1 * inv * w[lane], y2 = x2 * inv * w[lane + 64];
    const float* cp = cosb + (size_t)s * 128;
    const float* sp = sinb + (size_t)s * 128;
    float o1 = y1 * cp[lane] - y2 * sp[lane];
    float o2 = y2 * cp[lane + 64] + y1 * sp[lane + 64];
    p[lane] = f2bf(o1 * sc);
    p[lane + 64] = f2bf(o2 * sc);
}

// ---------------- V transpose ----------------
__global__ __launch_bounds__(256) void transpose_v(const u16* __restrict__ qkv,
                                                   u16* __restrict__ vT) {
    __shared__ u16 t[32][33];
    int bh = blockIdx.z, b = bh >> 2, kvh = bh & 3;
    int s0 = blockIdx.y * 32, d0 = blockIdx.x * 32;
    int tx = threadIdx.x, ty = threadIdx.y;
    const u16* src = qkv + (size_t)(b * 2048) * 3072 + 2560 + kvh * 128;
#pragma unroll
    for (int i = 0; i < 32; i += 8)
        t[ty + i][tx] = src[(size_t)(s0 + ty + i) * 3072 + d0 + tx];
    __syncthreads();
    u16* dst = vT + (size_t)bh * 128 * 2048;
#pragma unroll
    for (int i = 0; i < 32; i += 8)
        dst[(size_t)(d0 + ty + i) * 2048 + s0 + tx] = t[tx][ty + i];
}

// ---------------- causal flash attention v4: 8-wave split-tile, 2x occupancy --------
// Block (bh, pair): 512 thr = 8 waves. Waves 0-3 own q-tile A=pair (rows ws*16),
// waves 4-7 own q-tile B=31-pair. Same per-block totals as v3 (132 active
// wave-iterations, same MFMA / LDS-read / staged-byte counts) but LDS stays 64 KB
// while waves/block doubles -> 2 blocks/CU = 16 waves/CU (4/SIMD), double the
// latency-hiding of v3's 8 waves/CU. v3 counters: MfmaUtil 25, VALUBusy 41,
// Occupancy 18.4 -> stall-bound with only 2 waves/SIMD. Per-wave VGPR drops
// (single tile: qf[4]+o[8]) -> fits 128-reg ceiling for 4 waves/SIMD.
// Staging: 4 gl_lds/thread/tile (2 K + 2 V), steady-state vmcnt(4).
// Wave-level `kt <= myQt` branch is wave-uniform; barriers block-uniform.
__global__ __launch_bounds__(512, 4) void attn_kernel(const u16* __restrict__ qkv,
                                                      const u16* __restrict__ vT,
                                                      u16* __restrict__ out) {
    __shared__ u16 Ks[2][64 * 128];    // [buf][kv][16B-chunk ^ (kv&15)]
    __shared__ u16 VsT[2][128 * 64];   // [buf][d][16B-chunk ^ (d&7)]
    const int tid = threadIdx.x, wave = tid >> 6, lane = tid & 63;
    const int quad = lane >> 4, l16 = lane & 15;
    const int ws = wave & 3;           // row-group within my tile
    const int bh = blockIdx.x, b = bh >> 4, h = bh & 15, kvh = h >> 2;
    const int pair = blockIdx.y;
    const int qtA = pair, qtB = 31 - pair;
    const int myQt = (wave < 4) ? qtA : qtB;   // wave-uniform
    const int NT = qtB + 1;
    const size_t rowBase = (size_t)b * 2048;
    const int kcol0 = 2048 + kvh * 128;
    const u16* vTbase = vT + (size_t)(b * 4 + kvh) * 128 * 2048;

    const int qrow = myQt * 64 + ws * 16 + l16;  // this lane's q row

    // Q B-frags (K=32): lane l16 holds d = ks*32 + quad*8 + j
    bfrag qf[4];
    {
        const u16* qp = qkv + (rowBase + qrow) * 3072 + h * 128 + quad * 8;
#pragma unroll
        for (int ks = 0; ks < 4; ++ks) qf[ks] = *(const bfrag*)(qp + ks * 32);
    }
    asm volatile("s_waitcnt vmcnt(0)" ::: "memory");
#pragma unroll
    for (int ks = 0; ks < 4; ++ks) {
        uint4 t = __builtin_bit_cast(uint4, qf[ks]);
        asm volatile("" : "+v"(t.x), "+v"(t.y), "+v"(t.z), "+v"(t.w));
        qf[ks] = __builtin_bit_cast(bfrag, t);
    }

    // persistent stage pointers (pre-swizzled), 512 threads: 2 K + 2 V loads each
    const u16* kp[2];
    const u16* vp[2];
#pragma unroll
    for (int i = 0; i < 2; ++i) {  // Ks: 64 rows x 16 chunks = 1024
        int c = i * 512 + tid, kv = c >> 4, cp2 = c & 15;
        kp[i] = qkv + (rowBase + kv) * 3072 + kcol0 + (cp2 ^ (kv & 15)) * 8;
    }
#pragma unroll
    for (int i = 0; i < 2; ++i) {  // VsT: 128 rows x 8 chunks = 1024
        int c = i * 512 + tid, d = c >> 3, cp2 = c & 7;
        vp[i] = vTbase + (size_t)d * 2048 + (cp2 ^ (d & 7)) * 8;
    }

    f32x4 o[8] = {};
    float lrun = 0.f;

    // stage tile 0 -> buf 0; advance ptrs to tile 1
#pragma unroll
    for (int i = 0; i < 2; ++i) gl_lds16(kp[i], &Ks[0][(i * 512 + tid) * 8]);
#pragma unroll
    for (int i = 0; i < 2; ++i) gl_lds16(vp[i], &VsT[0][(i * 512 + tid) * 8]);
#pragma unroll
    for (int i = 0; i < 2; ++i) { kp[i] += 64 * 3072; vp[i] += 64; }

#pragma unroll 1
    for (int kt = 0; kt < NT; ++kt) {
        const int cur = kt & 1;
        if (kt + 1 < NT) {
#pragma unroll
            for (int i = 0; i < 2; ++i) gl_lds16(kp[i], &Ks[cur ^ 1][(i * 512 + tid) * 8]);
#pragma unroll
            for (int i = 0; i < 2; ++i) gl_lds16(vp[i], &VsT[cur ^ 1][(i * 512 + tid) * 8]);
#pragma unroll
            for (int i = 0; i < 2; ++i) { kp[i] += 64 * 3072; vp[i] += 64; }
            waitcnt_vm<4>();
        } else {
            waitcnt_vm<0>();
        }
        __builtin_amdgcn_s_barrier();
        asm volatile("" ::: "memory");

        if (kt <= myQt) {  // wave-uniform
            const int kv0 = kt * 64;

            // S^T = K * Q^T : 4 kv-subtiles x 1 q-subtile (scores in exp2-domain)
            f32x4 sa[4] = {};
            __builtin_amdgcn_s_setprio(1);
#pragma unroll
            for (int ks = 0; ks < 4; ++ks)
#pragma unroll
                for (int m = 0; m < 4; ++m) {
                    bfrag kf = *(const bfrag*)&Ks[cur][((m * 16 + l16) * 16 + ((ks * 4 + quad) ^ l16)) * 8];
                    sa[m] = __builtin_amdgcn_mfma_f32_16x16x32_bf16(kf, qf[ks], sa[m], 0, 0, 0);
                }
            __builtin_amdgcn_s_setprio(0);

            // no-max softmax: p = exp2(s); masked lanes -> -3e38 underflows to 0
            if (kv0 + 63 > myQt * 64 + ws * 16) {  // diagonal tile only
#pragma unroll
                for (int m = 0; m < 4; ++m)
#pragma unroll
                    for (int r = 0; r < 4; ++r)
                        if (kv0 + m * 16 + quad * 4 + r > qrow) sa[m][r] = -3e38f;
            }
            float rs = 0.f;
#pragma unroll
            for (int m = 0; m < 4; ++m)
#pragma unroll
                for (int r = 0; r < 4; ++r) {
                    float pe = exp2f(sa[m][r]);
                    sa[m][r] = pe;
                    rs += pe;
                }
            rs += __shfl_xor(rs, 16, 64);
            rs += __shfl_xor(rs, 32, 64);
            lrun += rs;

            // O^T += V^T * P^T  (K=16 MFMA; P^T C-layout IS the B-layout)
            sh4 pf[4];
#pragma unroll
            for (int m = 0; m < 4; ++m) pf[m] = pack4(sa[m]);
            __builtin_amdgcn_s_setprio(1);
#pragma unroll
            for (int k2 = 0; k2 < 4; ++k2) {
#pragma unroll
                for (int dt = 0; dt < 8; ++dt) {
                    int d = dt * 16 + l16;
                    int ch = k2 * 2 + (quad >> 1);
                    sh4 vf = *(const sh4*)&VsT[cur][(d * 8 + (ch ^ (l16 & 7))) * 8 + (quad & 1) * 4];
                    o[dt] = pv_mfma(vf, pf[k2], o[dt]);
                }
            }
            __builtin_amdgcn_s_setprio(0);
        }
        asm volatile("" ::: "memory");
        __builtin_amdgcn_s_barrier();  // all reads of buf[cur] done before overwrite
    }

    // epilogue: normalize, pack, store 8B per (lane, dtile)
    float inv = 1.0f / lrun;
    size_t orow = (rowBase + qrow) * 2048 + h * 128 + quad * 4;
#pragma unroll
    for (int dt = 0; dt < 8; ++dt) {
        float a0 = o[dt][0] * inv, a1 = o[dt][1] * inv;
        float a2 = o[dt][2] * inv, a3 = o[dt][3] * inv;
        uint2 pk;
        asm("v_cvt_pk_bf16_f32 %0, %1, %2" : "=v"(pk.x) : "v"(a0), "v"(a1));
        asm("v_cvt_pk_bf16_f32 %0, %1, %2" : "=v"(pk.y) : "v"(a2), "v"(a3));
        *(uint2*)(out + orow + dt * 16) = pk;
    }
}

extern "C" void kernel_launch(void* const* d_in, const int* in_sizes, int n_in,
                              void* d_out, int out_size, void* d_ws, size_t ws_size,
                              hipStream_t stream) {
    const float* hs   = (const float*)d_in[0];
    const float* cosb = (const float*)d_in[1];
    const float* sinb = (const float*)d_in[2];
    const float* Wq = (const float*)d_in[4];
    const float* Wk = (const float*)d_in[5];
    const float* Wv = (const float*)d_in[6];
    const float* Wo = (const float*)d_in[7];
    const float* qw = (const float*)d_in[8];
    const float* kw = (const float*)d_in[9];
    float* out = (float*)d_out;

    char* ws = (char*)d_ws;
    u16* hsb   = (u16*)(ws + 0);          // 16 MB: hs bf16; later reused as attn-out bf16
    u16* wqkvT = (u16*)(ws + 16777216);   // 12 MB
    u16* woT   = (u16*)(ws + 29360128);   // 8 MB
    u16* qkv   = (u16*)(ws + 37748736);   // 24 MB
    u16* vT    = (u16*)(ws + 62914560);   // 4 MB

    dim3 tb(32, 8);
    cvt_f32_bf16<<<8192, 256, 0, stream>>>(hs, hsb, 2097152);
    transpose_cvt<<<dim3(64, 64), tb, 0, stream>>>(Wq, wqkvT, 2048, 2048);
    transpose_cvt<<<dim3(16, 64), tb, 0, stream>>>(Wk, wqkvT + (size_t)2048 * 2048, 2048, 512);
    transpose_cvt<<<dim3(16, 64), tb, 0, stream>>>(Wv, wqkvT + (size_t)2560 * 2048, 2048, 512);
    transpose_cvt<<<dim3(64, 64), tb, 0, stream>>>(Wo, woT, 2048, 2048);

    // QKV projection: M=4096, N=3072, K=2048 -> BN=192: 16x16 = 256 blocks (no tail)
    gemm_p4<192, u16><<<dim3(16, 16), 512, 0, stream>>>(hsb, wqkvT, qkv, 2048, 3072);

    rmsrope<<<20480, 256, 0, stream>>>(qkv, cosb, sinb, qw, kw);
    transpose_v<<<dim3(4, 64, 8), tb, 0, stream>>>(qkv, vT);

    attn_kernel<<<dim3(32, 16), 512, 0, stream>>>(qkv, vT, hsb);

    // O projection: M=4096, N=2048, K=2048 -> BN=128: 16x16 = 256 blocks
    gemm_p4<128, float><<<dim3(16, 16), 512, 0, stream>>>(hsb, woT, out, 2048, 2048);
}

// Round 9
// 308.098 us; speedup vs baseline: 1.2937x; 1.0446x over previous
//
#include <hip/hip_runtime.h>
#include <stdint.h>

typedef unsigned short u16;
typedef __bf16 bfrag __attribute__((ext_vector_type(8)));   // 8 bf16 = 4 VGPRs (MFMA A/B, K=32)
typedef float f32x4 __attribute__((ext_vector_type(4)));    // MFMA C/D

#define LOG2E 1.44269504088896340736f

__device__ __forceinline__ u16 f2bf(float f) {
    unsigned u = __builtin_bit_cast(unsigned, f);
    u = (u + 0x7fffu + ((u >> 16) & 1u)) >> 16;
    return (u16)u;
}
__device__ __forceinline__ float bf2f(u16 x) {
    unsigned u = ((unsigned)x) << 16;
    return __builtin_bit_cast(float, u);
}

__device__ __forceinline__ void gl_lds16(const u16* g, u16* l) {
#if __has_builtin(__builtin_amdgcn_global_load_lds)
    __builtin_amdgcn_global_load_lds(
        (const __attribute__((address_space(1))) unsigned int*)g,
        (__attribute__((address_space(3))) unsigned int*)l, 16, 0, 0);
#else
    *(uint4*)l = *(const uint4*)g;
#endif
}

template <int N>
__device__ __forceinline__ void waitcnt_vm() {
    if constexpr (N == 0)      asm volatile("s_waitcnt vmcnt(0)" ::: "memory");
    else if constexpr (N == 4) asm volatile("s_waitcnt vmcnt(4)" ::: "memory");
    else if constexpr (N == 5) asm volatile("s_waitcnt vmcnt(5)" ::: "memory");
    else if constexpr (N == 6) asm volatile("s_waitcnt vmcnt(6)" ::: "memory");
    else if constexpr (N == 7) asm volatile("s_waitcnt vmcnt(7)" ::: "memory");
    else if constexpr (N == 8) asm volatile("s_waitcnt vmcnt(8)" ::: "memory");
}

// pack 4 f32 -> 2x u32 of bf16 pairs via v_cvt_pk_bf16_f32 (RNE)
__device__ __forceinline__ uint2 pack4(const f32x4& v) {
    uint2 u;
    asm("v_cvt_pk_bf16_f32 %0, %1, %2" : "=v"(u.x) : "v"(v[0]), "v"(v[1]));
    asm("v_cvt_pk_bf16_f32 %0, %1, %2" : "=v"(u.y) : "v"(v[2]), "v"(v[3]));
    return u;
}

// ---------------- fp32 -> bf16 elementwise ----------------
__global__ __launch_bounds__(256) void cvt_f32_bf16(const float* __restrict__ s,
                                                    u16* __restrict__ d, int n4) {
    int i = blockIdx.x * 256 + threadIdx.x;
    if (i < n4) {
        float4 v = ((const float4*)s)[i];
        uint2 o;
        o.x = (unsigned)f2bf(v.x) | ((unsigned)f2bf(v.y) << 16);
        o.y = (unsigned)f2bf(v.z) | ((unsigned)f2bf(v.w) << 16);
        ((uint2*)d)[i] = o;
    }
}

// ---------------- transpose + convert ----------------
__global__ __launch_bounds__(256) void transpose_cvt(const float* __restrict__ src,
                                                     u16* __restrict__ dst,
                                                     int rows, int cols) {
    __shared__ float tile[32][33];
    int c0 = blockIdx.x * 32, r0 = blockIdx.y * 32;
    int tx = threadIdx.x, ty = threadIdx.y;
#pragma unroll
    for (int i = 0; i < 32; i += 8)
        tile[ty + i][tx] = src[(size_t)(r0 + ty + i) * cols + c0 + tx];
    __syncthreads();
#pragma unroll
    for (int i = 0; i < 32; i += 8)
        dst[(size_t)(c0 + ty + i) * rows + r0 + tx] = f2bf(tile[tx][ty + i]);
}

// ---------------- phase-split GEMM (R4-proven p4 schedule, BN templated) -----------
// Unchanged from R7/R8 (best measured config).
template <int BN, typename OutT>
__global__ __launch_bounds__(512, 1) void gemm_p4(const u16* __restrict__ A,
                                                  const u16* __restrict__ B,
                                                  OutT* __restrict__ C,
                                                  int K, int ldc) {
    constexpr int BM = 256;
    constexpr int NF = BN / 32;
    constexpr int LB = BN / 64;
    constexpr int VW = 4 + LB;
    __shared__ __align__(16) u16 As[2][BM * 64];
    __shared__ __align__(16) u16 Bs[2][BN * 64];
    const int tid = threadIdx.x;
    const int wid = tid >> 6, lane = tid & 63;
    const int quad = lane >> 4, l16 = lane & 15;
    const int wm = wid >> 1, wn = wid & 1;
    const int bm = blockIdx.x * BM, bn = blockIdx.y * BN;
    const int NT = K >> 6;

    const u16* aSrc[4];
    const u16* bSrc[LB];
#pragma unroll
    for (int j = 0; j < 4; ++j) {
        int c = j * 512 + tid, row = c >> 3, ch = c & 7;
        aSrc[j] = A + (size_t)(bm + row) * K + (ch ^ (row & 7)) * 8;
    }
#pragma unroll
    for (int j = 0; j < LB; ++j) {
        int c = j * 512 + tid, row = c >> 3, ch = c & 7;
        bSrc[j] = B + (size_t)(bn + row) * K + (ch ^ (row & 7)) * 8;
    }

    const int swz = l16 & 7;
    const int aBase = (wm * 64 + l16) * 64;
    const int bBase = (wn * (BN / 2) + l16) * 64;
    const int c0 = (quad ^ swz) * 8;
    const int c1 = ((4 | quad) ^ swz) * 8;

    f32x4 acc[4][NF] = {};

#pragma unroll
    for (int j = 0; j < 4; ++j) gl_lds16(aSrc[j], &As[0][(j * 512 + tid) * 8]);
#pragma unroll
    for (int j = 0; j < LB; ++j) gl_lds16(bSrc[j], &Bs[0][(j * 512 + tid) * 8]);
#pragma unroll
    for (int j = 0; j < 4; ++j) gl_lds16(aSrc[j] + 64, &As[1][(j * 512 + tid) * 8]);
#pragma unroll
    for (int j = 0; j < LB; ++j) gl_lds16(bSrc[j] + 64, &Bs[1][(j * 512 + tid) * 8]);
    waitcnt_vm<VW>();
    __builtin_amdgcn_s_barrier();
    asm volatile("" ::: "memory");

    int koff = 128;
    for (int t = 0; t < NT; ++t) {
        const u16* ab = &As[t & 1][0];
        const u16* bb = &Bs[t & 1][0];

        bfrag a0[4], b0[NF], a1[4], b1[NF];
#pragma unroll
        for (int mf = 0; mf < 4; ++mf) a0[mf] = *(const bfrag*)&ab[aBase + mf * 1024 + c0];
#pragma unroll
        for (int nf = 0; nf < NF; ++nf) b0[nf] = *(const bfrag*)&bb[bBase + nf * 1024 + c0];
#pragma unroll
        for (int mf = 0; mf < 4; ++mf) a1[mf] = *(const bfrag*)&ab[aBase + mf * 1024 + c1];
#pragma unroll
        for (int nf = 0; nf < NF; ++nf) b1[nf] = *(const bfrag*)&bb[bBase + nf * 1024 + c1];

        __builtin_amdgcn_s_setprio(1);
#pragma unroll
        for (int mf = 0; mf < 4; ++mf)
#pragma unroll
            for (int nf = 0; nf < NF; ++nf)
                acc[mf][nf] = __builtin_amdgcn_mfma_f32_16x16x32_bf16(a0[mf], b0[nf], acc[mf][nf], 0, 0, 0);
        __builtin_amdgcn_s_setprio(0);

        asm volatile("s_waitcnt lgkmcnt(0)" ::: "memory");
        __builtin_amdgcn_s_barrier();
        asm volatile("" ::: "memory");

        if (t + 2 < NT) {
#pragma unroll
            for (int j = 0; j < 4; ++j) gl_lds16(aSrc[j] + koff, &As[t & 1][(j * 512 + tid) * 8]);
#pragma unroll
            for (int j = 0; j < LB; ++j) gl_lds16(bSrc[j] + koff, &Bs[t & 1][(j * 512 + tid) * 8]);
            koff += 64;
        }

        __builtin_amdgcn_s_setprio(1);
#pragma unroll
        for (int mf = 0; mf < 4; ++mf)
#pragma unroll
            for (int nf = 0; nf < NF; ++nf)
                acc[mf][nf] = __builtin_amdgcn_mfma_f32_16x16x32_bf16(a1[mf], b1[nf], acc[mf][nf], 0, 0, 0);
        __builtin_amdgcn_s_setprio(0);

        if (t + 2 < NT)      waitcnt_vm<VW>();
        else if (t + 1 < NT) waitcnt_vm<0>();
        if (t + 1 < NT) {
            __builtin_amdgcn_s_barrier();
            asm volatile("" ::: "memory");
        }
    }

#pragma unroll
    for (int mf = 0; mf < 4; ++mf)
#pragma unroll
        for (int nf = 0; nf < NF; ++nf)
#pragma unroll
            for (int r = 0; r < 4; ++r) {
                int row = bm + wm * 64 + mf * 16 + quad * 4 + r;
                int col = bn + wn * (BN / 2) + nf * 16 + l16;
                float v = acc[mf][nf][r];
                if constexpr (sizeof(OutT) == 2)
                    C[(size_t)row * ldc + col] = f2bf(v);
                else
                    C[(size_t)row * ldc + col] = v;
            }
}

// ---------------- RMSNorm + RoPE (q prescaled by softmax scale * log2e) ----------------
__global__ __launch_bounds__(256) void rmsrope(u16* __restrict__ qkv,
                                               const float* __restrict__ cosb,
                                               const float* __restrict__ sinb,
                                               const float* __restrict__ qw,
                                               const float* __restrict__ kw) {
    const float c1 = 0.08838834764831845f * LOG2E;
    int wave = threadIdx.x >> 6, lane = threadIdx.x & 63;
    int pi = blockIdx.x * 4 + wave;
    int m = pi / 20, hsel = pi % 20;
    int col0 = hsel < 16 ? hsel * 128 : 2048 + (hsel - 16) * 128;
    const float* w = hsel < 16 ? qw : kw;
    float sc = hsel < 16 ? c1 : 1.0f;
    int s = m & 2047;
    u16* p = qkv + (size_t)m * 3072 + col0;
    float x1 = bf2f(p[lane]), x2 = bf2f(p[lane + 64]);
    float ss = x1 * x1 + x2 * x2;
#pragma unroll
    for (int off = 32; off; off >>= 1) ss += __shfl_xor(ss, off, 64);
    float inv = rsqrtf(ss * (1.0f / 128.0f) + 1e-6f);
    float y1 = x1 * inv * w[lane], y2 = x2 * inv * w[lane + 64];
    const float* cp = cosb + (size_t)s * 128;
    const float* sp = sinb + (size_t)s * 128;
    float o1 = y1 * cp[lane] - y2 * sp[lane];
    float o2 = y2 * cp[lane + 64] + y1 * sp[lane + 64];
    p[lane] = f2bf(o1 * sc);
    p[lane + 64] = f2bf(o2 * sc);
}

// ---------------- V transpose ----------------
__global__ __launch_bounds__(256) void transpose_v(const u16* __restrict__ qkv,
                                                   u16* __restrict__ vT) {
    __shared__ u16 t[32][33];
    int bh = blockIdx.z, b = bh >> 2, kvh = bh & 3;
    int s0 = blockIdx.y * 32, d0 = blockIdx.x * 32;
    int tx = threadIdx.x, ty = threadIdx.y;
    const u16* src = qkv + (size_t)(b * 2048) * 3072 + 2560 + kvh * 128;
#pragma unroll
    for (int i = 0; i < 32; i += 8)
        t[ty + i][tx] = src[(size_t)(s0 + ty + i) * 3072 + d0 + tx];
    __syncthreads();
    u16* dst = vT + (size_t)bh * 128 * 2048;
#pragma unroll
    for (int i = 0; i < 32; i += 8)
        dst[(size_t)(d0 + ty + i) * 2048 + s0 + tx] = t[tx][ty + i];
}

// ---------------- causal flash attention v5: K-row perm -> K=32 PV, no V conflicts ---
// v4 counters: occupancy 2x'd (35.7%) but dur FLAT at 83.7us; SQ_LDS_BANK_CONFLICT
// 8.65M (~17% of CU cycles) from the PV ds_read_b64 pattern (row stride 128B -> d
// never reaches the bank index; 16/32 banks, 2 addrs/bank). v5 removes that class:
//  - K rows staged PERMUTED: LDS row x = 16m+4q+r holds kv = 32(m>>1)+8q+4(m&1)+r
//    (free: only the staging source address changes). QK^T's C-layout then leaves
//    each lane holding P for kv = 32ks2 + 8*quad + j, j=0..7 -> pk[2ks2],pk[2ks2+1]
//    ARE the K=32 B-frag verbatim (register renaming, no shuffles). V needs natural
//    kv order (permutation cancels: B slot k holds actual kv 32ks2+k).
//  - PV: 16x mfma_f32_16x16x32_bf16, A = V^T via ds_read_b128 with the gemm_p4
//    pattern (4-base chunk ^ (row&7)) -- measured ZERO conflicts in gemm_p4.
//    Half the PV MFMA pipe cycles (full-K instruction), half the V-read instrs.
//  - mask formula updated to the permuted kv; row-sum is permutation-invariant.
__global__ __launch_bounds__(512, 4) void attn_kernel(const u16* __restrict__ qkv,
                                                      const u16* __restrict__ vT,
                                                      u16* __restrict__ out) {
    __shared__ u16 Ks[2][64 * 128];    // [buf][row-pos][16B-chunk ^ (pos&15)] (rows PERMUTED)
    __shared__ u16 VsT[2][128 * 64];   // [buf][d][16B-chunk ^ (d&7)] (natural kv order)
    const int tid = threadIdx.x, wave = tid >> 6, lane = tid & 63;
    const int quad = lane >> 4, l16 = lane & 15;
    const int ws = wave & 3;           // row-group within my tile
    const int bh = blockIdx.x, b = bh >> 4, h = bh & 15, kvh = h >> 2;
    const int pair = blockIdx.y;
    const int qtA = pair, qtB = 31 - pair;
    const int myQt = (wave < 4) ? qtA : qtB;   // wave-uniform
    const int NT = qtB + 1;
    const size_t rowBase = (size_t)b * 2048;
    const int kcol0 = 2048 + kvh * 128;
    const u16* vTbase = vT + (size_t)(b * 4 + kvh) * 128 * 2048;

    const int qrow = myQt * 64 + ws * 16 + l16;  // this lane's q row

    // Q B-frags (K=32): lane l16 holds d = ks*32 + quad*8 + j
    bfrag qf[4];
    {
        const u16* qp = qkv + (rowBase + qrow) * 3072 + h * 128 + quad * 8;
#pragma unroll
        for (int ks = 0; ks < 4; ++ks) qf[ks] = *(const bfrag*)(qp + ks * 32);
    }
    asm volatile("s_waitcnt vmcnt(0)" ::: "memory");
#pragma unroll
    for (int ks = 0; ks < 4; ++ks) {
        uint4 t = __builtin_bit_cast(uint4, qf[ks]);
        asm volatile("" : "+v"(t.x), "+v"(t.y), "+v"(t.z), "+v"(t.w));
        qf[ks] = __builtin_bit_cast(bfrag, t);
    }

    // persistent stage pointers (pre-swizzled), 512 threads: 2 K + 2 V loads each.
    // K source row = PERMUTED: pos x -> kv 32*(m>>1) + 8*q + 4*(m&1) + r.
    const u16* kp[2];
    const u16* vp[2];
#pragma unroll
    for (int i = 0; i < 2; ++i) {  // Ks: 64 rows x 16 chunks = 1024
        int c = i * 512 + tid, pos = c >> 4, cp2 = c & 15;
        int m = pos >> 4, qd = (pos >> 2) & 3, r = pos & 3;
        int kvp = 32 * (m >> 1) + 8 * qd + 4 * (m & 1) + r;
        kp[i] = qkv + (rowBase + kvp) * 3072 + kcol0 + (cp2 ^ (pos & 15)) * 8;
    }
#pragma unroll
    for (int i = 0; i < 2; ++i) {  // VsT: 128 rows x 8 chunks = 1024
        int c = i * 512 + tid, d = c >> 3, cp2 = c & 7;
        vp[i] = vTbase + (size_t)d * 2048 + (cp2 ^ (d & 7)) * 8;
    }

    f32x4 o[8] = {};
    float lrun = 0.f;

    // stage tile 0 -> buf 0; advance ptrs to tile 1
#pragma unroll
    for (int i = 0; i < 2; ++i) gl_lds16(kp[i], &Ks[0][(i * 512 + tid) * 8]);
#pragma unroll
    for (int i = 0; i < 2; ++i) gl_lds16(vp[i], &VsT[0][(i * 512 + tid) * 8]);
#pragma unroll
    for (int i = 0; i < 2; ++i) { kp[i] += 64 * 3072; vp[i] += 64; }

#pragma unroll 1
    for (int kt = 0; kt < NT; ++kt) {
        const int cur = kt & 1;
        if (kt + 1 < NT) {
#pragma unroll
            for (int i = 0; i < 2; ++i) gl_lds16(kp[i], &Ks[cur ^ 1][(i * 512 + tid) * 8]);
#pragma unroll
            for (int i = 0; i < 2; ++i) gl_lds16(vp[i], &VsT[cur ^ 1][(i * 512 + tid) * 8]);
#pragma unroll
            for (int i = 0; i < 2; ++i) { kp[i] += 64 * 3072; vp[i] += 64; }
            waitcnt_vm<4>();
        } else {
            waitcnt_vm<0>();
        }
        __builtin_amdgcn_s_barrier();
        asm volatile("" ::: "memory");

        if (kt <= myQt) {  // wave-uniform
            const int kv0 = kt * 64;

            // S^T = K * Q^T (rows permuted; scores in exp2-domain)
            f32x4 sa[4] = {};
            __builtin_amdgcn_s_setprio(1);
#pragma unroll
            for (int ks = 0; ks < 4; ++ks)
#pragma unroll
                for (int m = 0; m < 4; ++m) {
                    bfrag kf = *(const bfrag*)&Ks[cur][((m * 16 + l16) * 16 + ((ks * 4 + quad) ^ l16)) * 8];
                    sa[m] = __builtin_amdgcn_mfma_f32_16x16x32_bf16(kf, qf[ks], sa[m], 0, 0, 0);
                }
            __builtin_amdgcn_s_setprio(0);

            // no-max softmax; masked -> -3e38 underflows to 0 in exp2.
            // sa[m][r] at lane quad holds kv = kv0 + 32*(m>>1) + 8*quad + 4*(m&1) + r.
            if (kv0 + 63 > myQt * 64 + ws * 16) {  // diagonal tile only
#pragma unroll
                for (int m = 0; m < 4; ++m)
#pragma unroll
                    for (int r = 0; r < 4; ++r)
                        if (kv0 + 32 * (m >> 1) + 8 * quad + 4 * (m & 1) + r > qrow)
                            sa[m][r] = -3e38f;
            }
            float rs = 0.f;
#pragma unroll
            for (int m = 0; m < 4; ++m)
#pragma unroll
                for (int r = 0; r < 4; ++r) {
                    float pe = exp2f(sa[m][r]);
                    sa[m][r] = pe;
                    rs += pe;
                }
            rs += __shfl_xor(rs, 16, 64);
            rs += __shfl_xor(rs, 32, 64);
            lrun += rs;

            // P -> bf16; pk[2ks2],pk[2ks2+1] form the K=32 B-frag directly
            uint2 pk[4];
#pragma unroll
            for (int m = 0; m < 4; ++m) pk[m] = pack4(sa[m]);
            bfrag pb[2];
            pb[0] = __builtin_bit_cast(bfrag, (uint4){pk[0].x, pk[0].y, pk[1].x, pk[1].y});
            pb[1] = __builtin_bit_cast(bfrag, (uint4){pk[2].x, pk[2].y, pk[3].x, pk[3].y});

            // O^T += V^T * P^T : K=32 MFMA, A = V^T b128 (gemm-proven conflict-free)
            __builtin_amdgcn_s_setprio(1);
#pragma unroll
            for (int ks2 = 0; ks2 < 2; ++ks2) {
#pragma unroll
                for (int dt = 0; dt < 8; ++dt) {
                    int d = dt * 16 + l16;
                    bfrag vf = *(const bfrag*)&VsT[cur][(d * 8 + ((ks2 * 4 + quad) ^ (d & 7))) * 8];
                    o[dt] = __builtin_amdgcn_mfma_f32_16x16x32_bf16(vf, pb[ks2], o[dt], 0, 0, 0);
                }
            }
            __builtin_amdgcn_s_setprio(0);
        }
        asm volatile("" ::: "memory");
        __builtin_amdgcn_s_barrier();  // all reads of buf[cur] done before overwrite
    }

    // epilogue: normalize, pack, store 8B per (lane, dtile)
    float inv = 1.0f / lrun;
    size_t orow = (rowBase + qrow) * 2048 + h * 128 + quad * 4;
#pragma unroll
    for (int dt = 0; dt < 8; ++dt) {
        float a0 = o[dt][0] * inv, a1 = o[dt][1] * inv;
        float a2 = o[dt][2] * inv, a3 = o[dt][3] * inv;
        uint2 pko;
        asm("v_cvt_pk_bf16_f32 %0, %1, %2" : "=v"(pko.x) : "v"(a0), "v"(a1));
        asm("v_cvt_pk_bf16_f32 %0, %1, %2" : "=v"(pko.y) : "v"(a2), "v"(a3));
        *(uint2*)(out + orow + dt * 16) = pko;
    }
}

extern "C" void kernel_launch(void* const* d_in, const int* in_sizes, int n_in,
                              void* d_out, int out_size, void* d_ws, size_t ws_size,
                              hipStream_t stream) {
    const float* hs   = (const float*)d_in[0];
    const float* cosb = (const float*)d_in[1];
    const float* sinb = (const float*)d_in[2];
    const float* Wq = (const float*)d_in[4];
    const float* Wk = (const float*)d_in[5];
    const float* Wv = (const float*)d_in[6];
    const float* Wo = (const float*)d_in[7];
    const float* qw = (const float*)d_in[8];
    const float* kw = (const float*)d_in[9];
    float* out = (float*)d_out;

    char* ws = (char*)d_ws;
    u16* hsb   = (u16*)(ws + 0);          // 16 MB: hs bf16; later reused as attn-out bf16
    u16* wqkvT = (u16*)(ws + 16777216);   // 12 MB
    u16* woT   = (u16*)(ws + 29360128);   // 8 MB
    u16* qkv   = (u16*)(ws + 37748736);   // 24 MB
    u16* vT    = (u16*)(ws + 62914560);   // 4 MB

    dim3 tb(32, 8);
    cvt_f32_bf16<<<8192, 256, 0, stream>>>(hs, hsb, 2097152);
    transpose_cvt<<<dim3(64, 64), tb, 0, stream>>>(Wq, wqkvT, 2048, 2048);
    transpose_cvt<<<dim3(16, 64), tb, 0, stream>>>(Wk, wqkvT + (size_t)2048 * 2048, 2048, 512);
    transpose_cvt<<<dim3(16, 64), tb, 0, stream>>>(Wv, wqkvT + (size_t)2560 * 2048, 2048, 512);
    transpose_cvt<<<dim3(64, 64), tb, 0, stream>>>(Wo, woT, 2048, 2048);

    // QKV projection: M=4096, N=3072, K=2048 -> BN=192: 16x16 = 256 blocks (no tail)
    gemm_p4<192, u16><<<dim3(16, 16), 512, 0, stream>>>(hsb, wqkvT, qkv, 2048, 3072);

    rmsrope<<<20480, 256, 0, stream>>>(qkv, cosb, sinb, qw, kw);
    transpose_v<<<dim3(4, 64, 8), tb, 0, stream>>>(qkv, vT);

    attn_kernel<<<dim3(32, 16), 512, 0, stream>>>(qkv, vT, hsb);

    // O projection: M=4096, N=2048, K=2048 -> BN=128: 16x16 = 256 blocks
    gemm_p4<128, float><<<dim3(16, 16), 512, 0, stream>>>(hsb, woT, out, 2048, 2048);
}